// Round 12
// baseline (312.539 us; speedup 1.0000x reference)
//
#include <hip/hip_runtime.h>

#define NN 4096
#define EE 131072
#define NP1 2048
#define NP2 1024

typedef __attribute__((ext_vector_type(8))) __bf16 bf16x8;
typedef __attribute__((ext_vector_type(4))) float f32x4;
typedef __attribute__((ext_vector_type(8))) unsigned short ushort8;

static __device__ inline unsigned short bfbits(__bf16 b) {
  union { __bf16 x; unsigned short u; } c; c.x = b; return c.u;
}
static __device__ inline void split2(float v, unsigned short& h, unsigned short& l) {
  __bf16 hb = (__bf16)v;
  float hf = (float)hb;
  __bf16 lb = (__bf16)(v - hf);
  h = bfbits(hb); l = bfbits(lb);
}

// Packed fragment layout for [R rows][K k] bf16 (R%16==0, K%32==0):
// 16x32 tile (rt,kt); chunk-in-tile = ((k>>3)&3)*16 + (r&15) == MFMA lane id.
static __device__ inline size_t pchunk(int r, int k, int NT) {
  return ((size_t)(r >> 4) * NT + (k >> 5)) * 64 + (((k >> 3) & 3) << 4) + (r & 15);
}

static __device__ inline void tsplit_body(const float* in, unsigned short* oh, unsigned short* ol,
                                          int R, int C, int c) {
  int lane = c & 63, tile = c >> 6;
  int NT = R >> 5;
  int kt = tile % NT, jt = tile / NT;
  int j = jt * 16 + (lane & 15);
  int k = kt * 32 + (lane >> 4) * 8;
  ushort8 hv, lv;
#pragma unroll
  for (int e = 0; e < 8; ++e) {
    unsigned short he, le;
    split2(in[(size_t)(k + e) * C + j], he, le);
    hv[e] = he; lv[e] = le;
  }
  *(ushort8*)&oh[(size_t)c * 8] = hv;
  *(ushort8*)&ol[(size_t)c * 8] = lv;
}

// ---------------- fused prep: edge histogram + weight conversions + p-norms ----------------

__global__ __launch_bounds__(256) void prep_all(
    const int* __restrict__ esrc, const int* __restrict__ edst,
    int* __restrict__ cnt_src, int* __restrict__ cnt_dst,
    const float* w0, const float* w1, const float* w2, const float* w3, const float* w4,
    unsigned short* o0h, unsigned short* o0l, unsigned short* o1h, unsigned short* o1l,
    unsigned short* o2h, unsigned short* o2l, unsigned short* o3h, unsigned short* o3l,
    unsigned short* o4h, unsigned short* o4l,
    const float* p0, const float* p1, float* pnrm) {
  __shared__ float red[4];
  int b = blockIdx.x;
  int tid = threadIdx.x;
  if (b < EE / 256) {
    int e = b * 256 + tid;
    atomicAdd(&cnt_src[esrc[e]], 1);
    atomicAdd(&cnt_dst[edst[e]], 1);
  } else if (b < EE / 256 + 288) {
    int g = (b - EE / 256) * 256 + tid;
    if (g < 4096)        tsplit_body(w0, o0h, o0l, 128, 256, g);
    else if (g < 20480)  tsplit_body(w1, o1h, o1l, 256, 512, g - 4096);
    else if (g < 53248)  tsplit_body(w2, o2h, o2l, 512, 512, g - 20480);
    else if (g < 69632)  tsplit_body(w3, o3h, o3l, 512, 256, g - 53248);
    else                 tsplit_body(w4, o4h, o4l, 256, 128, g - 69632);
  } else {
    int which = b - (EE / 256 + 288);
    const float* p = which ? p1 : p0;
    int C = which ? 512 : 256;
    float acc = 0.f;
    for (int j = tid; j < C; j += 256) { float v = p[j]; acc += v * v; }
    for (int o = 32; o > 0; o >>= 1) acc += __shfl_down(acc, o);
    if ((tid & 63) == 0) red[tid >> 6] = acc;
    __syncthreads();
    if (tid == 0) pnrm[which] = sqrtf(red[0] + red[1] + red[2] + red[3]);
  }
}

// both exclusive scans in one launch; block 0 also emits dis0
__global__ __launch_bounds__(1024) void scan2(const int* __restrict__ cnt_dst,
                                              const int* __restrict__ cnt_src,
                                              int* __restrict__ csc_off, int* __restrict__ csr_off,
                                              float* __restrict__ dis0, int n) {
  __shared__ int tmp[4096];
  const int* in = blockIdx.x ? cnt_src : cnt_dst;
  int* out = blockIdx.x ? csr_off : csc_off;
  int tid = threadIdx.x;
  for (int i = tid; i < n; i += 1024) {
    int v = in[i];
    tmp[i] = v;
    if (blockIdx.x == 0) dis0[i] = rsqrtf((float)v + 1.0f);
  }
  __syncthreads();
  for (int off = 1; off < n; off <<= 1) {
    int v[4];
    int c = 0;
    for (int i = tid; i < n; i += 1024) { v[c++] = (i >= off) ? tmp[i - off] : 0; }
    __syncthreads();
    c = 0;
    for (int i = tid; i < n; i += 1024) { tmp[i] += v[c++]; }
    __syncthreads();
  }
  for (int i = tid; i < n; i += 1024) out[i + 1] = tmp[i];
  if (tid == 0) out[0] = 0;
}

__global__ void scatter_kernel(const int* __restrict__ src, const int* __restrict__ dst,
                               const int* __restrict__ csc_off, const int* __restrict__ csr_off,
                               int* __restrict__ fill_dst, int* __restrict__ fill_src,
                               int* __restrict__ csc_src, int* __restrict__ csr_dst, int E) {
  int e = blockIdx.x * blockDim.x + threadIdx.x;
  if (e < E) {
    int s = src[e], d = dst[e];
    int p = atomicAdd(&fill_dst[d], 1);
    csc_src[csc_off[d] + p] = s;
    int q = atomicAdd(&fill_src[s], 1);
    csr_dst[csr_off[s] + q] = d;
  }
}

// ---------------- scoring / topk ----------------

__global__ void score_key(const float* __restrict__ X, const float* __restrict__ p,
                          const float* __restrict__ pn, float* __restrict__ s,
                          unsigned long long* __restrict__ keys, int C) {
  int i = blockIdx.x;
  int tid = threadIdx.x;
  float acc = 0.f;
  for (int j = tid; j < C; j += 256) acc += X[(size_t)i * C + j] * p[j];
  for (int o = 32; o > 0; o >>= 1) acc += __shfl_down(acc, o);
  __shared__ float red[4];
  if ((tid & 63) == 0) red[tid >> 6] = acc;
  __syncthreads();
  if (tid == 0) {
    float sv = tanhf((red[0] + red[1] + red[2] + red[3]) / pn[0]);
    s[i] = sv;
    unsigned u = __float_as_uint(sv);
    unsigned m = (u & 0x80000000u) ? ~u : (u | 0x80000000u);
    keys[i] = (((unsigned long long)(~m)) << 32) | (unsigned)i;  // desc value, asc index
  }
}

// partial rank: block (bx,by) counts keys[by*512..+512) against candidates [bx*256..+256)
__global__ __launch_bounds__(256) void rank_count(const unsigned long long* __restrict__ keys,
                                                  int* __restrict__ rank) {
  __shared__ unsigned long long kk[512];
  int tid = threadIdx.x;
  int cand = blockIdx.x * 256 + tid;
  int base = blockIdx.y * 512;
  kk[tid] = keys[base + tid];
  kk[tid + 256] = keys[base + tid + 256];
  __syncthreads();
  unsigned long long kc = keys[cand];
  int c = 0;
#pragma unroll 8
  for (int t = 0; t < 512; ++t) c += (kk[t] < kc) ? 1 : 0;
  atomicAdd(&rank[cand], c);
}

// place by rank; optionally emit cntk (1 if kept) for the sparse-deg path
__global__ void rank_place(const float* __restrict__ s, const int* __restrict__ rank, int k, int n,
                           int* __restrict__ kept, int* __restrict__ perm, float* __restrict__ vals,
                           int* __restrict__ cntk) {
  int i = blockIdx.x * blockDim.x + threadIdx.x;
  if (i < n) {
    int r = rank[i];
    int isk = (r < k) ? 1 : 0;
    if (isk) { perm[r] = i; vals[r] = s[i]; kept[i] = r; }
    else kept[i] = -1;
    if (cntk) cntk[i] = isk;
  }
}

// pool-gather + gate + dis-scale + transpose-split packed ([256 ch][2048 nodes])
__global__ void pool_tsplit_p(const float* __restrict__ X, const int* __restrict__ perm,
                              const float* __restrict__ vals, const float* __restrict__ dis,
                              unsigned short* __restrict__ h, unsigned short* __restrict__ l) {
  int c = blockIdx.x * blockDim.x + threadIdx.x;
  int tile = c >> 6, lno = c & 63;
  int kt = tile & 63, jt = tile >> 6;   // NT = 2048/32 = 64
  int j = jt * 16 + (lno & 15);
  int k0 = kt * 32 + (lno >> 4) * 8;
  ushort8 hv, lv;
#pragma unroll
  for (int e = 0; e < 8; ++e) {
    int node = k0 + e;
    float sc = vals[node] * dis[node];
    float v = X[(size_t)perm[node] * 256 + j] * sc;
    unsigned short he, le;
    split2(v, he, le);
    hv[e] = he; lv[e] = le;
  }
  *(ushort8*)&h[(size_t)c * 8] = hv;
  *(ushort8*)&l[(size_t)c * 8] = lv;
}

// fused pool1 siblings: pooled-row packed split (blocks 0..255) + two packed gathers (256..2303)
__global__ __launch_bounds__(256) void pool1_misc(
    const float* __restrict__ res1, const int* __restrict__ perm1, const float* __restrict__ vals1,
    unsigned short* __restrict__ x2h, unsigned short* __restrict__ x2l,
    const unsigned short* __restrict__ B1rm, const unsigned short* __restrict__ B1t,
    unsigned short* __restrict__ Gh2, unsigned short* __restrict__ Hh2) {
  int b = blockIdx.x;
  int tid = threadIdx.x;
  if (b < 256) {
    int c = b * 256 + tid;                // over NP2*512/8 chunks
    int lane = c & 63, tile = c >> 6;
    int kt = tile & 15, rt = tile >> 4;   // NT = 512/32 = 16
    int r = rt * 16 + (lane & 15);
    int k0 = kt * 32 + (lane >> 4) * 8;
    float v = vals1[r];
    const float* src = res1 + (size_t)perm1[r] * 512 + k0;
    ushort8 hv, lv;
#pragma unroll
    for (int e = 0; e < 8; ++e) {
      unsigned short he, le;
      split2(src[e] * v, he, le);
      hv[e] = he; lv[e] = le;
    }
    *(ushort8*)&x2h[(size_t)c * 8] = hv;
    *(ushort8*)&x2l[(size_t)c * 8] = lv;
  } else {
    int idx = b - 256;
    int mat = idx >> 10;
    int c = (idx & 1023) * 256 + tid;     // over NP2*NP1/8 chunks
    const unsigned short* in = mat ? B1t : B1rm;
    unsigned short* outp = mat ? Hh2 : Gh2;
    const int NT = NP1 >> 5;              // 64
    int lane = c & 63, tile = c >> 6;
    int kt = tile % NT, at = tile / NT;
    int a = at * 16 + (lane & 15);
    int sub = lane >> 4;
    int p = perm1[a];
    size_t sc = ((size_t)(p >> 4) * NT + kt) * 64 + sub * 16 + (p & 15);
    *(ushort8*)&outp[(size_t)c * 8] = *(const ushort8*)&in[sc * 8];
  }
}

// ---------------- augment 0 (fused): sparse 2-path rows + kept-edge counts ----------------

__global__ __launch_bounds__(256) void augcnt(const int* __restrict__ csr_off,
                                              const int* __restrict__ csr_dst,
                                              const int* __restrict__ kept,
                                              const int* __restrict__ perm,
                                              unsigned short* __restrict__ rm,
                                              const int* __restrict__ esrc,
                                              const int* __restrict__ edst,
                                              int* __restrict__ cntk) {
  __shared__ float acc[NP1];
  int b = blockIdx.x;
  if (b < NP1) {
    int ki = b;
    int r = perm[ki];
    for (int t = threadIdx.x; t < NP1; t += 256) acc[t] = 0.f;
    __syncthreads();
    int s = csr_off[r], e = csr_off[r + 1];
    int nm = e - s;
    int wave = threadIdx.x >> 6, lane = threadIdx.x & 63;
    for (int m = wave; m <= nm; m += 4) {
      int k = (m < nm) ? csr_dst[s + m] : r;
      int s2 = csr_off[k], e2 = csr_off[k + 1];
      int n2 = e2 - s2;
      for (int t = lane; t <= n2; t += 64) {
        int j = (t < n2) ? csr_dst[s2 + t] : k;
        int kj = kept[j];
        if (kj >= 0) atomicAdd(&acc[kj], 1.0f);
      }
    }
    __syncthreads();
    if (threadIdx.x == 0) acc[ki] += 1.0f;  // +I on pooled graph
    __syncthreads();
    int tid = threadIdx.x;
    ushort8 hv;
#pragma unroll
    for (int e8 = 0; e8 < 8; ++e8) hv[e8] = bfbits((__bf16)acc[tid * 8 + e8]);
    size_t dst = (((size_t)(ki >> 4)) * 64 + (tid >> 2)) * 64 + (size_t)(tid & 3) * 16 + (ki & 15);
    *(ushort8*)&rm[dst * 8] = hv;
  } else {
    int e = (b - NP1) * 256 + threadIdx.x;
    if (kept[esrc[e]] >= 0) atomicAdd(&cntk[edst[e]], 1);
  }
}

// fused: packed transpose of B1rm (blocks 0..1023) + dis1 from sparse degs (blocks 1024..1535)
__global__ __launch_bounds__(256) void degtp(const unsigned short* __restrict__ in,
                                             unsigned short* __restrict__ outp, int n,
                                             const int* __restrict__ csc_off,
                                             const int* __restrict__ csc_src,
                                             const int* __restrict__ cntk,
                                             const int* __restrict__ perm,
                                             float* __restrict__ dis) {
  __shared__ unsigned short t[64][72];
  int b = blockIdx.x;
  if (b < 1024) {
    int r0 = (b >> 5) * 64, c0 = (b & 31) * 64;
    int NT = n >> 5;
    for (int q = threadIdx.x; q < 512; q += 256) {
      int lt = q >> 6, l = q & 63;
      int rt = lt >> 1, kt2 = lt & 1;
      int r = rt * 16 + (l & 15), k = kt2 * 32 + (l >> 4) * 8;
      ushort8 v = *(const ushort8*)&in[pchunk(r0 + r, c0 + k, NT) * 8];
      *(ushort8*)&t[r][k] = v;
    }
    __syncthreads();
    for (int q = threadIdx.x; q < 512; q += 256) {
      int lt = q >> 6, l = q & 63;
      int jt = lt >> 1, kt2 = lt & 1;
      int j = jt * 16 + (l & 15), k = kt2 * 32 + (l >> 4) * 8;
      ushort8 v;
#pragma unroll
      for (int e = 0; e < 8; ++e) v[e] = t[k + e][j];
      *(ushort8*)&outp[pchunk(c0 + j, r0 + k, NT) * 8] = v;
    }
  } else {
    int bid = b - 1024;
    int wid = threadIdx.x >> 6, lane = threadIdx.x & 63;
    int c = bid * 4 + wid;
    int r = perm[c];
    int s = csc_off[r], e = csc_off[r + 1];
    int sum = 0;
    for (int t2 = s + lane; t2 < e; t2 += 64) sum += cntk[csc_src[t2]];
    for (int o = 32; o > 0; o >>= 1) sum += __shfl_down(sum, o);
    if (lane == 0) dis[c] = rsqrtf((float)(sum + cntk[r] + 1));
  }
}

// ---------------- sparse aggregation ----------------

// A-first spmm fused with packed bf16 split output (gcn0)
template <int C>
__global__ __launch_bounds__(256) void spmm_presplit(const float* __restrict__ X,
                                                     const int* __restrict__ off,
                                                     const int* __restrict__ srcs,
                                                     const float* __restrict__ dis,
                                                     unsigned short* __restrict__ h,
                                                     unsigned short* __restrict__ l) {
  __shared__ float buf[4][C];
  constexpr int VEC = C / 64;
  int w = threadIdx.x >> 6, lane = threadIdx.x & 63;
  int c = blockIdx.x * 4 + w;
  int j = lane * VEC;
  float dc = dis[c];
  float acc[VEC];
  const float* p = X + (size_t)c * C + j;
#pragma unroll
  for (int u = 0; u < VEC; ++u) acc[u] = dc * p[u];
  int s = off[c], e = off[c + 1];
  for (int t = s; t < e; ++t) {
    int sr = srcs[t];
    float ds = dis[sr];
    const float* q = X + (size_t)sr * C + j;
#pragma unroll
    for (int u = 0; u < VEC; ++u) acc[u] += ds * q[u];
  }
#pragma unroll
  for (int u = 0; u < VEC; ++u) buf[w][j + u] = dc * acc[u];
  __syncthreads();
  constexpr int NC = C / 8;
  if (lane < NC) {
    const float* src = &buf[w][lane * 8];
    ushort8 hv, lv;
#pragma unroll
    for (int e2 = 0; e2 < 8; ++e2) {
      unsigned short he, le;
      split2(src[e2], he, le);
      hv[e2] = he; lv[e2] = le;
    }
    size_t ch = pchunk(c, lane * 8, C >> 5);
    *(ushort8*)&h[ch * 8] = hv;
    *(ushort8*)&l[ch * 8] = lv;
  }
}

// X-first spmm (gcn4): out = relu(dis[c]*(sum of pre-scaled rows) + bias)
template <int C>
__global__ __launch_bounds__(256) void spmm_gather_v(const float* __restrict__ Y,
                                                     const int* __restrict__ off,
                                                     const int* __restrict__ srcs,
                                                     const float* __restrict__ dis,
                                                     const float* __restrict__ bias,
                                                     float* __restrict__ out) {
  constexpr int VEC = C / 64;
  int w = threadIdx.x >> 6, lane = threadIdx.x & 63;
  int c = blockIdx.x * 4 + w;
  int j = lane * VEC;
  float acc[VEC];
  const float* p = Y + (size_t)c * C + j;
#pragma unroll
  for (int u = 0; u < VEC; ++u) acc[u] = p[u];
  int s = off[c], e = off[c + 1];
  for (int t = s; t < e; ++t) {
    const float* q = Y + (size_t)srcs[t] * C + j;
#pragma unroll
    for (int u = 0; u < VEC; ++u) acc[u] += q[u];
  }
  float d = dis[c];
  float* o = out + (size_t)c * C + j;
#pragma unroll
  for (int u = 0; u < VEC; ++u) o[u] = fmaxf(d * acc[u] + bias[j + u], 0.0f);
}

// ---------------- combines ----------------

// combine S partials -> packed bf16 hi/lo row-major (for Z = B1^T Xs)
template <int S>
__global__ void ep_zsplit(const float* __restrict__ p, unsigned short* __restrict__ h,
                          unsigned short* __restrict__ l, int M, int N) {
  int t = blockIdx.x * blockDim.x + threadIdx.x;
  int tile = t >> 6, w = t & 63;
  int NT = N >> 5;
  int rt = tile / NT, kt = tile % NT;
  int r = rt * 16 + (w & 15);
  int k = kt * 32 + (w >> 4) * 8;
  const float* p0 = p + (size_t)r * N + k;
  ushort8 hv, lv;
#pragma unroll
  for (int e = 0; e < 8; ++e) {
    float v = p0[e];
#pragma unroll
    for (int s = 1; s < S; ++s) v += p0[(size_t)s * M * N + e];
    unsigned short he, le;
    split2(v, he, le);
    hv[e] = he; lv[e] = le;
  }
  *(ushort8*)&h[(size_t)t * 8] = hv;
  *(ushort8*)&l[(size_t)t * 8] = lv;
}

// unpool + fold split-K epilogue: x = res[r] + (kept? relu(rs*(sum partials)+bias) : 0) -> packed split
template <int S, int RSQ>
__global__ void unpool_ep_split(const float* __restrict__ res, const float* __restrict__ pscr,
                                const int* __restrict__ kept, const float* __restrict__ rs,
                                const float* __restrict__ bias,
                                unsigned short* __restrict__ h, unsigned short* __restrict__ l,
                                int M, int C) {
  int c = blockIdx.x * blockDim.x + threadIdx.x;
  int lane = c & 63, tile = c >> 6;
  int NT = C >> 5;
  int kt = tile % NT, rt = tile / NT;
  int r = rt * 16 + (lane & 15);
  int j0 = kt * 32 + (lane >> 4) * 8;
  int kv = kept[r];
  float rsv = 0.f;
  if (kv >= 0) { rsv = rs[kv]; if (RSQ) rsv = rsqrtf(rsv); }
  ushort8 hv, lv;
#pragma unroll
  for (int e = 0; e < 8; ++e) {
    float v = res[(size_t)r * C + j0 + e];
    if (kv >= 0) {
      float a = 0.f;
#pragma unroll
      for (int s = 0; s < S; ++s) a += pscr[((size_t)s * M + kv) * C + j0 + e];
      v += fmaxf(rsv * a + bias[j0 + e], 0.0f);
    }
    unsigned short he, le;
    split2(v, he, le);
    hv[e] = he; lv[e] = le;
  }
  *(ushort8*)&h[(size_t)c * 8] = hv;
  *(ushort8*)&l[(size_t)c * 8] = lv;
}

// combine S partials (+I) -> PACKED transpose-split B2t directly, + column sums into deg
template <int S>
__global__ void ep_aug_cs2(const float* __restrict__ p, unsigned short* __restrict__ th,
                           unsigned short* __restrict__ tl, float* __restrict__ deg, int n) {
  int c = blockIdx.x * 256 + threadIdx.x;
  int r0 = blockIdx.y * 64;
  int NT = n >> 5;
  float cs = 0.f;
  for (int g = 0; g < 8; ++g) {
    float vbuf[8];
#pragma unroll
    for (int e = 0; e < 8; ++e) {
      int r = r0 + g * 8 + e;
      float v = 0.f;
#pragma unroll
      for (int s = 0; s < S; ++s) v += p[((size_t)s * n + r) * n + c];
      if (r == c) v += 1.0f;
      vbuf[e] = v;
      cs += v;
    }
    ushort8 hv, lv;
#pragma unroll
    for (int e = 0; e < 8; ++e) {
      unsigned short he, le;
      split2(vbuf[e], he, le);
      hv[e] = he; lv[e] = le;
    }
    size_t ch = pchunk(c, r0 + g * 8, NT);
    *(ushort8*)&th[ch * 8] = hv;
    *(ushort8*)&tl[ch * 8] = lv;
  }
  atomicAdd(&deg[c], cs);
}

// ---------------- bf16-split MFMA GEMM, 32x32/wave ----------------
// S>1: partial to C + z*M*N. S==1 EPI: 0 plain; 1 rowscale; 2 rowscale+packed-T-split;
// 3 rowscale+bias+relu; 4 bias+relu. RSQ: rs -> rsqrt(rs).
template <int EPI, int AL, int BL, int KK, int S, int RSQ>
__global__ __launch_bounds__(256) void gemm16(
    const unsigned short* __restrict__ Ah, const unsigned short* __restrict__ Al,
    const unsigned short* __restrict__ Bh, const unsigned short* __restrict__ Bl,
    int M, int N, const float* __restrict__ rs, const float* __restrict__ bias,
    float* __restrict__ C, unsigned short* __restrict__ Th, unsigned short* __restrict__ Tl) {
  static_assert(KK % 32 == 0, "K");
  constexpr int KSTEPS = KK / 32;
  const int NT = (KK * S) >> 5;
  const int gx = gridDim.x;
  int id = blockIdx.y * gx + blockIdx.x;
  int cpx = (gx * gridDim.y) >> 3;
  int sid = (id & 7) * cpx + (id >> 3);
  const int bx = sid % gx, by = sid / gx;
  const int z = (S > 1) ? blockIdx.z : 0;
  const int wid = threadIdx.x >> 6, lane = threadIdx.x & 63;
  const int i0 = by * 64 + (wid >> 1) * 32;
  const int j0 = bx * 64 + (wid & 1) * 32;
  const int lr = lane & 15, lk = lane >> 4;
  size_t aoff[2], boff[2];
#pragma unroll
  for (int t = 0; t < 2; ++t) {
    aoff[t] = ((size_t)((i0 >> 4) + t) * NT + z * (KK >> 5)) * 512 + lane * 8;
    boff[t] = ((size_t)((j0 >> 4) + t) * NT + z * (KK >> 5)) * 512 + lane * 8;
  }
  const f32x4 zf = {0.f, 0.f, 0.f, 0.f};
  f32x4 acc[2][2];
  acc[0][0] = zf; acc[0][1] = zf; acc[1][0] = zf; acc[1][1] = zf;

  bf16x8 ahf[4][2], bhf[4][2], alf[4][2], blf[4][2];
  auto loadk = [&](int kk, int b) {
    size_t o = (size_t)kk * 512;
    ahf[b][0] = *(const bf16x8*)(Ah + aoff[0] + o);
    ahf[b][1] = *(const bf16x8*)(Ah + aoff[1] + o);
    bhf[b][0] = *(const bf16x8*)(Bh + boff[0] + o);
    bhf[b][1] = *(const bf16x8*)(Bh + boff[1] + o);
    if constexpr (AL) {
      alf[b][0] = *(const bf16x8*)(Al + aoff[0] + o);
      alf[b][1] = *(const bf16x8*)(Al + aoff[1] + o);
    }
    if constexpr (BL) {
      blf[b][0] = *(const bf16x8*)(Bl + boff[0] + o);
      blf[b][1] = *(const bf16x8*)(Bl + boff[1] + o);
    }
  };
  auto domm = [&](int b) {
#pragma unroll
    for (int am = 0; am < 2; ++am)
#pragma unroll
      for (int bn = 0; bn < 2; ++bn) {
        acc[am][bn] = __builtin_amdgcn_mfma_f32_16x16x32_bf16(ahf[b][am], bhf[b][bn], acc[am][bn], 0, 0, 0);
        if constexpr (BL)
          acc[am][bn] = __builtin_amdgcn_mfma_f32_16x16x32_bf16(ahf[b][am], blf[b][bn], acc[am][bn], 0, 0, 0);
        if constexpr (AL)
          acc[am][bn] = __builtin_amdgcn_mfma_f32_16x16x32_bf16(alf[b][am], bhf[b][bn], acc[am][bn], 0, 0, 0);
      }
  };

  loadk(0, 0);
  if constexpr (KSTEPS > 1) loadk(1, 1);
  if constexpr (KSTEPS > 2) loadk(2, 2);
#pragma unroll
  for (int kk = 0; kk < KSTEPS; ++kk) {
    const int cur = kk & 3;
    if (kk + 3 < KSTEPS) loadk(kk + 3, (cur + 3) & 3);
    domm(cur);
  }

#pragma unroll
  for (int am = 0; am < 2; ++am)
#pragma unroll
    for (int bn = 0; bn < 2; ++bn) {
      int ib = i0 + 16 * am + lk * 4;
      int j = j0 + 16 * bn + lr;
      f32x4 a = acc[am][bn];
      if constexpr (S > 1) {
#pragma unroll
        for (int r = 0; r < 4; ++r) C[((size_t)z * M + ib + r) * N + j] = a[r];
      } else if constexpr (EPI == 0) {
#pragma unroll
        for (int r = 0; r < 4; ++r) C[(size_t)(ib + r) * N + j] = a[r];
      } else if constexpr (EPI == 1) {
#pragma unroll
        for (int r = 0; r < 4; ++r) {
          float rsv = rs[ib + r];
          if (RSQ) rsv = rsqrtf(rsv);
          C[(size_t)(ib + r) * N + j] = rsv * a[r];
        }
      } else if constexpr (EPI == 2) {
        unsigned long long hp = 0, lp = 0;
#pragma unroll
        for (int r = 0; r < 4; ++r) {
          float rsv = rs[ib + r];
          if (RSQ) rsv = rsqrtf(rsv);
          unsigned short hv, lv;
          split2(rsv * a[r], hv, lv);
          hp |= ((unsigned long long)hv) << (16 * r);
          lp |= ((unsigned long long)lv) << (16 * r);
        }
        size_t c = pchunk(j, ib, M >> 5);
        *(unsigned long long*)&Th[c * 8 + (ib & 7)] = hp;
        *(unsigned long long*)&Tl[c * 8 + (ib & 7)] = lp;
      } else if constexpr (EPI == 3) {
#pragma unroll
        for (int r = 0; r < 4; ++r) {
          float rsv = rs[ib + r];
          if (RSQ) rsv = rsqrtf(rsv);
          C[(size_t)(ib + r) * N + j] = fmaxf(rsv * a[r] + bias[j], 0.0f);
        }
      } else {
#pragma unroll
        for (int r = 0; r < 4; ++r)
          C[(size_t)(ib + r) * N + j] = fmaxf(a[r] + bias[j], 0.0f);
      }
    }
}

// ---------------- bf16-split MFMA GEMM, 64x64/wave (split-K partials) ----------------
template <int AL, int BL, int KK, int S>
__global__ __launch_bounds__(256) void gemm64(
    const unsigned short* __restrict__ Ah, const unsigned short* __restrict__ Al,
    const unsigned short* __restrict__ Bh, const unsigned short* __restrict__ Bl,
    int M, int N, float* __restrict__ C) {
  static_assert(KK % 32 == 0, "K");
  constexpr int KSTEPS = KK / 32;
  const int NT = (KK * S) >> 5;
  const int gx = gridDim.x;
  int id = blockIdx.y * gx + blockIdx.x;
  int cpx = (gx * gridDim.y) >> 3;
  int sid = (id & 7) * cpx + (id >> 3);
  const int bx = sid % gx, by = sid / gx;
  const int z = blockIdx.z;
  const int wid = threadIdx.x >> 6, lane = threadIdx.x & 63;
  const int i0 = by * 128 + (wid >> 1) * 64;
  const int j0 = bx * 128 + (wid & 1) * 64;
  const int lr = lane & 15, lk = lane >> 4;
  size_t aoff[4], boff[4];
#pragma unroll
  for (int t = 0; t < 4; ++t) {
    aoff[t] = ((size_t)((i0 >> 4) + t) * NT + z * (KK >> 5)) * 512 + lane * 8;
    boff[t] = ((size_t)((j0 >> 4) + t) * NT + z * (KK >> 5)) * 512 + lane * 8;
  }
  const f32x4 zf = {0.f, 0.f, 0.f, 0.f};
  f32x4 acc[4][4];
#pragma unroll
  for (int a = 0; a < 4; ++a)
#pragma unroll
    for (int b = 0; b < 4; ++b) acc[a][b] = zf;

  bf16x8 ahf[2][4], bhf[2][4], alf[2][4], blf[2][4];
  auto loadk = [&](int kk, int b) {
    size_t o = (size_t)kk * 512;
#pragma unroll
    for (int t = 0; t < 4; ++t) {
      ahf[b][t] = *(const bf16x8*)(Ah + aoff[t] + o);
      bhf[b][t] = *(const bf16x8*)(Bh + boff[t] + o);
      if constexpr (AL) alf[b][t] = *(const bf16x8*)(Al + aoff[t] + o);
      if constexpr (BL) blf[b][t] = *(const bf16x8*)(Bl + boff[t] + o);
    }
  };
  auto domm = [&](int b) {
#pragma unroll
    for (int am = 0; am < 4; ++am)
#pragma unroll
      for (int bn = 0; bn < 4; ++bn) {
        acc[am][bn] = __builtin_amdgcn_mfma_f32_16x16x32_bf16(ahf[b][am], bhf[b][bn], acc[am][bn], 0, 0, 0);
        if constexpr (BL)
          acc[am][bn] = __builtin_amdgcn_mfma_f32_16x16x32_bf16(ahf[b][am], blf[b][bn], acc[am][bn], 0, 0, 0);
        if constexpr (AL)
          acc[am][bn] = __builtin_amdgcn_mfma_f32_16x16x32_bf16(alf[b][am], bhf[b][bn], acc[am][bn], 0, 0, 0);
      }
  };

  loadk(0, 0);
#pragma unroll
  for (int kk = 0; kk < KSTEPS; ++kk) {
    const int cur = kk & 1;
    if (kk + 1 < KSTEPS) loadk(kk + 1, cur ^ 1);
    domm(cur);
  }

#pragma unroll
  for (int am = 0; am < 4; ++am)
#pragma unroll
    for (int bn = 0; bn < 4; ++bn) {
      int ib = i0 + 16 * am + lk * 4;
      int j = j0 + 16 * bn + lr;
      f32x4 a = acc[am][bn];
#pragma unroll
      for (int r = 0; r < 4; ++r) C[((size_t)z * M + ib + r) * N + j] = a[r];
    }
}

// ---------------- launch ----------------

extern "C" void kernel_launch(void* const* d_in, const int* in_sizes, int n_in,
                              void* d_out, int out_size, void* d_ws, size_t ws_size,
                              hipStream_t stream) {
  (void)in_sizes; (void)n_in; (void)out_size; (void)ws_size;
  const float* x  = (const float*)d_in[0];
  const int* ei   = (const int*)d_in[1];
  const int* esrc = ei;
  const int* edst = ei + EE;
  const float* w0 = (const float*)d_in[2];
  const float* b0 = (const float*)d_in[3];
  const float* w1 = (const float*)d_in[4];
  const float* b1 = (const float*)d_in[5];
  const float* w2 = (const float*)d_in[6];
  const float* b2 = (const float*)d_in[7];
  const float* w3 = (const float*)d_in[8];
  const float* b3 = (const float*)d_in[9];
  const float* w4 = (const float*)d_in[10];
  const float* b4 = (const float*)d_in[11];
  const float* p0 = (const float*)d_in[12];
  const float* p1 = (const float*)d_in[13];
  float* out = (float*)d_out;

  char* ws = (char*)d_ws;
  size_t off = 0;
  auto alloc = [&](size_t b) { void* p = ws + off; off += (b + 255) & ~(size_t)255; return p; };

  int* csc_off = (int*)alloc(4 * (NN + 1));
  int* csr_off = (int*)alloc(4 * (NN + 1));
  int* csc_src = (int*)alloc(4 * EE);
  int* csr_dst = (int*)alloc(4 * EE);

  // zeroed region: 4 count arrays + deg2 + rank0 + rank1
  size_t zero_bytes = 4 * NN * 4 + 4 * NP2 + 4 * NN + 4 * NP1;
  int* cnts    = (int*)alloc(zero_bytes);
  int* cnt_dst = cnts;
  int* cnt_src = cnts + NN;
  int* fill_dst = cnts + 2 * NN;
  int* fill_src = cnts + 3 * NN;
  float* deg2 = (float*)(cnts + 4 * NN);
  int* rank0 = (int*)(deg2 + NP2);
  int* rank1 = rank0 + NN;

  int* cntk  = (int*)alloc(4 * NN);
  int* kept0 = (int*)alloc(4 * NN);
  int* perm0 = (int*)alloc(4 * NP1);
  int* kept1 = (int*)alloc(4 * NP1);
  int* perm1 = (int*)alloc(4 * NP2);
  float* dis0 = (float*)alloc(4 * NN);
  float* dis1 = (float*)alloc(4 * NP1);
  float* pnrm = (float*)alloc(8);
  float* s0   = (float*)alloc(4 * NN);
  float* vals0 = (float*)alloc(4 * NP1);
  float* s1   = (float*)alloc(4 * NP1);
  float* vals1 = (float*)alloc(4 * NP2);
  unsigned long long* keys0 = (unsigned long long*)alloc(8 * NN);
  unsigned long long* keys1 = (unsigned long long*)alloc(8 * NP1);

  const size_t MB = 1024 * 1024;
  // 16MB region: Gh2/Hh2 gathers (0..8MB); later B2t splits (4..8MB, over dead Hh2)
  char* regB1 = (char*)alloc(16 * MB);
  unsigned short* Gh2 = (unsigned short*)regB1;
  unsigned short* Hh2 = (unsigned short*)(regB1 + 4 * MB);
  unsigned short* B2th = (unsigned short*)(regB1 + 4 * MB);
  unsigned short* B2tl = (unsigned short*)(regB1 + 6 * MB);
  float* pscr = (float*)alloc(16 * MB);  // split-K partials

  unsigned short* B1rm = (unsigned short*)alloc(8 * MB);  // packed bf16 (exact)
  unsigned short* B1t  = (unsigned short*)alloc(8 * MB);  // packed bf16 transpose (exact)
  float* res0 = (float*)alloc(4 * MB);
  float* res1 = (float*)alloc(4 * MB);
  float* yreg = (float*)alloc(4 * MB);   // y4 (4096x128)
  char* ytreg = (char*)alloc(4 * MB);    // Y2t h+l / Y3t h+l
  unsigned short* Y2th = (unsigned short*)ytreg;
  unsigned short* Y2tl = (unsigned short*)(ytreg + 1 * MB);
  unsigned short* Y3th = (unsigned short*)ytreg;
  unsigned short* Y3tl = (unsigned short*)(ytreg + 1 * MB);
  char* xsreg = (char*)alloc(4 * MB);    // x3 h+l -> x4 h+l
  unsigned short* x3h = (unsigned short*)xsreg;
  unsigned short* x3l = (unsigned short*)(xsreg + 2 * MB);
  unsigned short* x4h = (unsigned short*)xsreg;
  unsigned short* x4l = (unsigned short*)(xsreg + 2 * MB);
  unsigned short* xh = (unsigned short*)alloc(1 * MB);   // Gh (4096x128 split)
  unsigned short* xl = (unsigned short*)alloc(1 * MB);
  char* xsm = (char*)alloc(2 * MB);      // x1t h+l -> Z h+l -> x2 h+l
  unsigned short* x1th = (unsigned short*)xsm;
  unsigned short* x1tl = (unsigned short*)(xsm + 1 * MB);
  unsigned short* Zh = (unsigned short*)xsm;
  unsigned short* Zl = (unsigned short*)(xsm + 1 * MB);
  unsigned short* x2h = (unsigned short*)xsm;
  unsigned short* x2l = (unsigned short*)(xsm + 1 * MB);
  unsigned short* Wt0h = (unsigned short*)alloc(256 * 128 * 2);
  unsigned short* Wt0l = (unsigned short*)alloc(256 * 128 * 2);
  unsigned short* Wt1h = (unsigned short*)alloc(512 * 256 * 2);
  unsigned short* Wt1l = (unsigned short*)alloc(512 * 256 * 2);
  unsigned short* Wt2h = (unsigned short*)alloc(512 * 512 * 2);
  unsigned short* Wt2l = (unsigned short*)alloc(512 * 512 * 2);
  unsigned short* Wt3h = (unsigned short*)alloc(256 * 512 * 2);
  unsigned short* Wt3l = (unsigned short*)alloc(256 * 512 * 2);
  unsigned short* Wt4h = (unsigned short*)alloc(128 * 256 * 2);
  unsigned short* Wt4l = (unsigned short*)alloc(128 * 256 * 2);

  hipMemsetAsync(cnts, 0, zero_bytes, stream);

  // graph build + weight conversions + p-norms
  prep_all<<<EE / 256 + 288 + 2, 256, 0, stream>>>(
      esrc, edst, cnt_src, cnt_dst, w0, w1, w2, w3, w4,
      Wt0h, Wt0l, Wt1h, Wt1l, Wt2h, Wt2l, Wt3h, Wt3l, Wt4h, Wt4l, p0, p1, pnrm);
  scan2<<<2, 1024, 0, stream>>>(cnt_dst, cnt_src, csc_off, csr_off, dis0, NN);
  scatter_kernel<<<EE / 256, 256, 0, stream>>>(esrc, edst, csc_off, csr_off,
                                               fill_dst, fill_src, csc_src, csr_dst, EE);

  // gcn0 (A-first): G = dis ⊙ (M+I)^T (dis ⊙ x) -> packed split; res0 = relu(G W0 + b0)
  spmm_presplit<128><<<NN / 4, 256, 0, stream>>>(x, csc_off, csc_src, dis0, xh, xl);
  gemm16<4, 1, 1, 128, 1, 0><<<dim3(4, 64), 256, 0, stream>>>(xh, xl, Wt0h, Wt0l,
                                                              NN, 256, nullptr, b0, res0, nullptr, nullptr);

  // pool0
  score_key<<<NN, 256, 0, stream>>>(res0, p0, pnrm + 0, s0, keys0, 256);
  rank_count<<<dim3(NN / 256, NN / 512), 256, 0, stream>>>(keys0, rank0);
  rank_place<<<NN / 256, 256, 0, stream>>>(s0, rank0, NP1, NN, kept0, perm0, vals0, cntk);

  // augment0 (fused): packed B1rm rows + kept-edge counts; then transpose + dis1 (fused)
  augcnt<<<NP1 + EE / 256, 256, 0, stream>>>(csr_off, csr_dst, kept0, perm0, B1rm,
                                             esrc, edst, cntk);
  degtp<<<1024 + NP1 / 4, 256, 0, stream>>>(B1rm, B1t, NP1, csc_off, csc_src, cntk, perm0, dis1);

  // gcn1 (A-first): Z = B1^T (dis1 ⊙ x1); res1 = relu(dis1 ⊙ (Z W1) + b1)
  pool_tsplit_p<<<(NP1 * 256 / 8) / 256, 256, 0, stream>>>(res0, perm0, vals0, dis1, x1th, x1tl);
  gemm16<0, 0, 1, 1024, 2, 0><<<dim3(4, 32, 2), 256, 0, stream>>>(B1t, nullptr, x1th, x1tl,
                                                                  NP1, 256, nullptr, nullptr, pscr, nullptr, nullptr);
  ep_zsplit<2><<<(NP1 * 256 / 8) / 256, 256, 0, stream>>>(pscr, Zh, Zl, NP1, 256);
  gemm16<3, 1, 1, 256, 1, 0><<<dim3(8, 32), 256, 0, stream>>>(Zh, Zl, Wt1h, Wt1l,
                                                              NP1, 512, dis1, b1, res1, nullptr, nullptr);

  // pool1
  score_key<<<NP1, 256, 0, stream>>>(res1, p1, pnrm + 1, s1, keys1, 512);
  rank_count<<<dim3(NP1 / 256, NP1 / 512), 256, 0, stream>>>(keys1, rank1);
  rank_place<<<NP1 / 256, 256, 0, stream>>>(s1, rank1, NP2, NP1, kept1, perm1, vals1, nullptr);

  // pool1 pooled-features split + both packed gathers (1 fused launch)
  pool1_misc<<<256 + 2048, 256, 0, stream>>>(res1, perm1, vals1, x2h, x2l,
                                             B1rm, B1t, Gh2, Hh2);

  // augment1: dense exact GEMM (split-K) -> packed B2t + colsums
  gemm64<0, 0, 512, 4><<<dim3(8, 8, 4), 256, 0, stream>>>(Gh2, nullptr, Hh2, nullptr,
                                                          NP2, NP2, pscr);
  ep_aug_cs2<4><<<dim3(NP2 / 256, NP2 / 64), 256, 0, stream>>>(pscr, B2th, B2tl, deg2, NP2);

  // gcn2 (bottleneck, X-first); dis2 = rsqrt(deg2) folded into epilogues
  gemm16<2, 1, 1, 512, 1, 1><<<dim3(8, 16), 256, 0, stream>>>(x2h, x2l, Wt2h, Wt2l,
                                                              NP2, 512, deg2, nullptr, nullptr, Y2th, Y2tl);
  gemm16<0, 1, 1, 512, 2, 0><<<dim3(8, 16, 2), 256, 0, stream>>>(B2th, B2tl, Y2th, Y2tl,
                                                                 NP2, 512, nullptr, nullptr, pscr, nullptr, nullptr);

  // up1: unpool + gcn2-combine folded, emit packed x3
  unpool_ep_split<2, 1><<<(NP1 * 512 / 8) / 256, 256, 0, stream>>>(res1, pscr, kept1, deg2, b2,
                                                                   x3h, x3l, NP2, 512);
  gemm16<2, 1, 1, 512, 1, 0><<<dim3(4, 32), 256, 0, stream>>>(x3h, x3l, Wt3h, Wt3l,
                                                              NP1, 256, dis1, nullptr, nullptr, Y3th, Y3tl);
  gemm64<0, 1, 256, 8><<<dim3(2, 16, 8), 256, 0, stream>>>(B1t, nullptr, Y3th, Y3tl,
                                                           NP1, 256, pscr);

  // up0: unpool + gcn3-combine folded, emit packed x4
  unpool_ep_split<8, 0><<<(NN * 256 / 8) / 256, 256, 0, stream>>>(res0, pscr, kept0, dis1, b3,
                                                                  x4h, x4l, NP1, 256);
  gemm16<1, 1, 1, 256, 1, 0><<<dim3(2, 64), 256, 0, stream>>>(x4h, x4l, Wt4h, Wt4l,
                                                              NN, 128, dis0, nullptr, yreg, nullptr, nullptr);
  spmm_gather_v<128><<<NN / 4, 256, 0, stream>>>(yreg, csc_off, csc_src, dis0, b4, out);
}

// Round 13
// 294.700 us; speedup vs baseline: 1.0605x; 1.0605x over previous
//
#include <hip/hip_runtime.h>

#define NN 4096
#define EE 131072
#define NP1 2048
#define NP2 1024

typedef __attribute__((ext_vector_type(8))) __bf16 bf16x8;
typedef __attribute__((ext_vector_type(4))) float f32x4;
typedef __attribute__((ext_vector_type(8))) unsigned short ushort8;

static __device__ inline unsigned short bfbits(__bf16 b) {
  union { __bf16 x; unsigned short u; } c; c.x = b; return c.u;
}
static __device__ inline void split2(float v, unsigned short& h, unsigned short& l) {
  __bf16 hb = (__bf16)v;
  float hf = (float)hb;
  __bf16 lb = (__bf16)(v - hf);
  h = bfbits(hb); l = bfbits(lb);
}

// Packed fragment layout for [R rows][K k] bf16 (R%16==0, K%32==0):
// 16x32 tile (rt,kt); chunk-in-tile = ((k>>3)&3)*16 + (r&15) == MFMA lane id.
static __device__ inline size_t pchunk(int r, int k, int NT) {
  return ((size_t)(r >> 4) * NT + (k >> 5)) * 64 + (((k >> 3) & 3) << 4) + (r & 15);
}

static __device__ inline void tsplit_body(const float* in, unsigned short* oh, unsigned short* ol,
                                          int R, int C, int c) {
  int lane = c & 63, tile = c >> 6;
  int NT = R >> 5;
  int kt = tile % NT, jt = tile / NT;
  int j = jt * 16 + (lane & 15);
  int k = kt * 32 + (lane >> 4) * 8;
  ushort8 hv, lv;
#pragma unroll
  for (int e = 0; e < 8; ++e) {
    unsigned short he, le;
    split2(in[(size_t)(k + e) * C + j], he, le);
    hv[e] = he; lv[e] = le;
  }
  *(ushort8*)&oh[(size_t)c * 8] = hv;
  *(ushort8*)&ol[(size_t)c * 8] = lv;
}

// ---------------- fused prep: edge histogram + weight conversions + p-norms ----------------

__global__ __launch_bounds__(256) void prep_all(
    const int* __restrict__ esrc, const int* __restrict__ edst,
    int* __restrict__ cnt_src, int* __restrict__ cnt_dst,
    const float* w0, const float* w1, const float* w2, const float* w3, const float* w4,
    unsigned short* o0h, unsigned short* o0l, unsigned short* o1h, unsigned short* o1l,
    unsigned short* o2h, unsigned short* o2l, unsigned short* o3h, unsigned short* o3l,
    unsigned short* o4h, unsigned short* o4l,
    const float* p0, const float* p1, float* pnrm) {
  __shared__ float red[4];
  int b = blockIdx.x;
  int tid = threadIdx.x;
  if (b < EE / 256) {
    int e = b * 256 + tid;
    atomicAdd(&cnt_src[esrc[e]], 1);
    atomicAdd(&cnt_dst[edst[e]], 1);
  } else if (b < EE / 256 + 288) {
    int g = (b - EE / 256) * 256 + tid;
    if (g < 4096)        tsplit_body(w0, o0h, o0l, 128, 256, g);
    else if (g < 20480)  tsplit_body(w1, o1h, o1l, 256, 512, g - 4096);
    else if (g < 53248)  tsplit_body(w2, o2h, o2l, 512, 512, g - 20480);
    else if (g < 69632)  tsplit_body(w3, o3h, o3l, 512, 256, g - 53248);
    else                 tsplit_body(w4, o4h, o4l, 256, 128, g - 69632);
  } else {
    int which = b - (EE / 256 + 288);
    const float* p = which ? p1 : p0;
    int C = which ? 512 : 256;
    float acc = 0.f;
    for (int j = tid; j < C; j += 256) { float v = p[j]; acc += v * v; }
    for (int o = 32; o > 0; o >>= 1) acc += __shfl_down(acc, o);
    if ((tid & 63) == 0) red[tid >> 6] = acc;
    __syncthreads();
    if (tid == 0) pnrm[which] = sqrtf(red[0] + red[1] + red[2] + red[3]);
  }
}

// both exclusive scans in one launch (register-serial + 1024-partial scan); block 0 emits dis0
__global__ __launch_bounds__(1024) void scan2(const int* __restrict__ cnt_dst,
                                              const int* __restrict__ cnt_src,
                                              int* __restrict__ csc_off, int* __restrict__ csr_off,
                                              float* __restrict__ dis0, int n) {
  __shared__ int part[1024];
  const int* in = blockIdx.x ? cnt_src : cnt_dst;
  int* out = blockIdx.x ? csr_off : csc_off;
  int tid = threadIdx.x;
  int base = tid * 4;
  int v[4];
  int s = 0;
#pragma unroll
  for (int e = 0; e < 4; ++e) {
    int x = in[base + e];
    v[e] = x; s += x;
    if (blockIdx.x == 0) dis0[base + e] = rsqrtf((float)x + 1.0f);
  }
  part[tid] = s;
  __syncthreads();
  for (int off2 = 1; off2 < 1024; off2 <<= 1) {
    int t = (tid >= off2) ? part[tid - off2] : 0;
    __syncthreads();
    part[tid] += t;
    __syncthreads();
  }
  int run = part[tid] - s;  // exclusive prefix of this thread's chunk
#pragma unroll
  for (int e = 0; e < 4; ++e) { run += v[e]; out[base + e + 1] = run; }
  if (tid == 0) out[0] = 0;
}

__global__ void scatter_kernel(const int* __restrict__ src, const int* __restrict__ dst,
                               const int* __restrict__ csc_off, const int* __restrict__ csr_off,
                               int* __restrict__ fill_dst, int* __restrict__ fill_src,
                               int* __restrict__ csc_src, int* __restrict__ csr_dst, int E) {
  int e = blockIdx.x * blockDim.x + threadIdx.x;
  if (e < E) {
    int s = src[e], d = dst[e];
    int p = atomicAdd(&fill_dst[d], 1);
    csc_src[csc_off[d] + p] = s;
    int q = atomicAdd(&fill_src[s], 1);
    csr_dst[csr_off[s] + q] = d;
  }
}

// ---------------- scoring / topk ----------------

__global__ void score_key(const float* __restrict__ X, const float* __restrict__ p,
                          const float* __restrict__ pn, float* __restrict__ s,
                          unsigned long long* __restrict__ keys, int C) {
  int i = blockIdx.x;
  int tid = threadIdx.x;
  float acc = 0.f;
  for (int j = tid; j < C; j += 256) acc += X[(size_t)i * C + j] * p[j];
  for (int o = 32; o > 0; o >>= 1) acc += __shfl_down(acc, o);
  __shared__ float red[4];
  if ((tid & 63) == 0) red[tid >> 6] = acc;
  __syncthreads();
  if (tid == 0) {
    float sv = tanhf((red[0] + red[1] + red[2] + red[3]) / pn[0]);
    s[i] = sv;
    unsigned u = __float_as_uint(sv);
    unsigned m = (u & 0x80000000u) ? ~u : (u | 0x80000000u);
    keys[i] = (((unsigned long long)(~m)) << 32) | (unsigned)i;  // desc value, asc index
  }
}

// partial rank: block (bx,by) counts keys[by*256..+256) against candidates [bx*256..+256)
__global__ __launch_bounds__(256) void rank_count(const unsigned long long* __restrict__ keys,
                                                  int* __restrict__ rank) {
  __shared__ unsigned long long kk[256];
  int tid = threadIdx.x;
  int cand = blockIdx.x * 256 + tid;
  int base = blockIdx.y * 256;
  kk[tid] = keys[base + tid];
  __syncthreads();
  unsigned long long kc = keys[cand];
  int c = 0;
#pragma unroll 8
  for (int t = 0; t < 256; ++t) c += (kk[t] < kc) ? 1 : 0;
  atomicAdd(&rank[cand], c);
}

// place by rank; optionally emit cntk (1 if kept) for the sparse-deg path
__global__ void rank_place(const float* __restrict__ s, const int* __restrict__ rank, int k, int n,
                           int* __restrict__ kept, int* __restrict__ perm, float* __restrict__ vals,
                           int* __restrict__ cntk) {
  int i = blockIdx.x * blockDim.x + threadIdx.x;
  if (i < n) {
    int r = rank[i];
    int isk = (r < k) ? 1 : 0;
    if (isk) { perm[r] = i; vals[r] = s[i]; kept[i] = r; }
    else kept[i] = -1;
    if (cntk) cntk[i] = isk;
  }
}

// pool-gather + gate + dis-scale + transpose-split packed ([256 ch][2048 nodes])
__global__ void pool_tsplit_p(const float* __restrict__ X, const int* __restrict__ perm,
                              const float* __restrict__ vals, const float* __restrict__ dis,
                              unsigned short* __restrict__ h, unsigned short* __restrict__ l) {
  int c = blockIdx.x * blockDim.x + threadIdx.x;
  int tile = c >> 6, lno = c & 63;
  int kt = tile & 63, jt = tile >> 6;   // NT = 2048/32 = 64
  int j = jt * 16 + (lno & 15);
  int k0 = kt * 32 + (lno >> 4) * 8;
  ushort8 hv, lv;
#pragma unroll
  for (int e = 0; e < 8; ++e) {
    int node = k0 + e;
    float sc = vals[node] * dis[node];
    float v = X[(size_t)perm[node] * 256 + j] * sc;
    unsigned short he, le;
    split2(v, he, le);
    hv[e] = he; lv[e] = le;
  }
  *(ushort8*)&h[(size_t)c * 8] = hv;
  *(ushort8*)&l[(size_t)c * 8] = lv;
}

// fused pool1 siblings: pooled-row packed split (blocks 0..255) + two packed gathers (256..2303)
__global__ __launch_bounds__(256) void pool1_misc(
    const float* __restrict__ res1, const int* __restrict__ perm1, const float* __restrict__ vals1,
    unsigned short* __restrict__ x2h, unsigned short* __restrict__ x2l,
    const unsigned short* __restrict__ B1rm, const unsigned short* __restrict__ B1t,
    unsigned short* __restrict__ Gh2, unsigned short* __restrict__ Hh2) {
  int b = blockIdx.x;
  int tid = threadIdx.x;
  if (b < 256) {
    int c = b * 256 + tid;                // over NP2*512/8 chunks
    int lane = c & 63, tile = c >> 6;
    int kt = tile & 15, rt = tile >> 4;   // NT = 512/32 = 16
    int r = rt * 16 + (lane & 15);
    int k0 = kt * 32 + (lane >> 4) * 8;
    float v = vals1[r];
    const float* src = res1 + (size_t)perm1[r] * 512 + k0;
    ushort8 hv, lv;
#pragma unroll
    for (int e = 0; e < 8; ++e) {
      unsigned short he, le;
      split2(src[e] * v, he, le);
      hv[e] = he; lv[e] = le;
    }
    *(ushort8*)&x2h[(size_t)c * 8] = hv;
    *(ushort8*)&x2l[(size_t)c * 8] = lv;
  } else {
    int idx = b - 256;
    int mat = idx >> 10;
    int c = (idx & 1023) * 256 + tid;     // over NP2*NP1/8 chunks
    const unsigned short* in = mat ? B1t : B1rm;
    unsigned short* outp = mat ? Hh2 : Gh2;
    const int NT = NP1 >> 5;              // 64
    int lane = c & 63, tile = c >> 6;
    int kt = tile % NT, at = tile / NT;
    int a = at * 16 + (lane & 15);
    int sub = lane >> 4;
    int p = perm1[a];
    size_t sc = ((size_t)(p >> 4) * NT + kt) * 64 + sub * 16 + (p & 15);
    *(ushort8*)&outp[(size_t)c * 8] = *(const ushort8*)&in[sc * 8];
  }
}

// ---------------- augment 0 (fused): sparse 2-path rows + kept-edge counts ----------------

__global__ __launch_bounds__(256) void augcnt(const int* __restrict__ csr_off,
                                              const int* __restrict__ csr_dst,
                                              const int* __restrict__ kept,
                                              const int* __restrict__ perm,
                                              unsigned short* __restrict__ rm,
                                              const int* __restrict__ esrc,
                                              const int* __restrict__ edst,
                                              int* __restrict__ cntk) {
  __shared__ float acc[NP1];
  int b = blockIdx.x;
  if (b < NP1) {
    int ki = b;
    int r = perm[ki];
    for (int t = threadIdx.x; t < NP1; t += 256) acc[t] = 0.f;
    __syncthreads();
    int s = csr_off[r], e = csr_off[r + 1];
    int nm = e - s;
    int wave = threadIdx.x >> 6, lane = threadIdx.x & 63;
    for (int m = wave; m <= nm; m += 4) {
      int k = (m < nm) ? csr_dst[s + m] : r;
      int s2 = csr_off[k], e2 = csr_off[k + 1];
      int n2 = e2 - s2;
      for (int t = lane; t <= n2; t += 64) {
        int j = (t < n2) ? csr_dst[s2 + t] : k;
        int kj = kept[j];
        if (kj >= 0) atomicAdd(&acc[kj], 1.0f);
      }
    }
    __syncthreads();
    if (threadIdx.x == 0) acc[ki] += 1.0f;  // +I on pooled graph
    __syncthreads();
    int tid = threadIdx.x;
    ushort8 hv;
#pragma unroll
    for (int e8 = 0; e8 < 8; ++e8) hv[e8] = bfbits((__bf16)acc[tid * 8 + e8]);
    size_t dst = (((size_t)(ki >> 4)) * 64 + (tid >> 2)) * 64 + (size_t)(tid & 3) * 16 + (ki & 15);
    *(ushort8*)&rm[dst * 8] = hv;
  } else {
    int e = (b - NP1) * 256 + threadIdx.x;
    if (kept[esrc[e]] >= 0) atomicAdd(&cntk[edst[e]], 1);
  }
}

// fused: packed transpose of B1rm (blocks 0..1023) + dis1 from sparse degs (blocks 1024..1535)
__global__ __launch_bounds__(256) void degtp(const unsigned short* __restrict__ in,
                                             unsigned short* __restrict__ outp, int n,
                                             const int* __restrict__ csc_off,
                                             const int* __restrict__ csc_src,
                                             const int* __restrict__ cntk,
                                             const int* __restrict__ perm,
                                             float* __restrict__ dis) {
  __shared__ unsigned short t[64][72];
  int b = blockIdx.x;
  if (b < 1024) {
    int r0 = (b >> 5) * 64, c0 = (b & 31) * 64;
    int NT = n >> 5;
    for (int q = threadIdx.x; q < 512; q += 256) {
      int lt = q >> 6, l = q & 63;
      int rt = lt >> 1, kt2 = lt & 1;
      int r = rt * 16 + (l & 15), k = kt2 * 32 + (l >> 4) * 8;
      ushort8 v = *(const ushort8*)&in[pchunk(r0 + r, c0 + k, NT) * 8];
      *(ushort8*)&t[r][k] = v;
    }
    __syncthreads();
    for (int q = threadIdx.x; q < 512; q += 256) {
      int lt = q >> 6, l = q & 63;
      int jt = lt >> 1, kt2 = lt & 1;
      int j = jt * 16 + (l & 15), k = kt2 * 32 + (l >> 4) * 8;
      ushort8 v;
#pragma unroll
      for (int e = 0; e < 8; ++e) v[e] = t[k + e][j];
      *(ushort8*)&outp[pchunk(c0 + j, r0 + k, NT) * 8] = v;
    }
  } else {
    int bid = b - 1024;
    int wid = threadIdx.x >> 6, lane = threadIdx.x & 63;
    int c = bid * 4 + wid;
    int r = perm[c];
    int s = csc_off[r], e = csc_off[r + 1];
    int sum = 0;
    for (int t2 = s + lane; t2 < e; t2 += 64) sum += cntk[csc_src[t2]];
    for (int o = 32; o > 0; o >>= 1) sum += __shfl_down(sum, o);
    if (lane == 0) dis[c] = rsqrtf((float)(sum + cntk[r] + 1));
  }
}

// ---------------- sparse aggregation ----------------

// A-first spmm fused with packed bf16 split output (gcn0)
template <int C>
__global__ __launch_bounds__(256) void spmm_presplit(const float* __restrict__ X,
                                                     const int* __restrict__ off,
                                                     const int* __restrict__ srcs,
                                                     const float* __restrict__ dis,
                                                     unsigned short* __restrict__ h,
                                                     unsigned short* __restrict__ l) {
  __shared__ float buf[4][C];
  constexpr int VEC = C / 64;
  int w = threadIdx.x >> 6, lane = threadIdx.x & 63;
  int c = blockIdx.x * 4 + w;
  int j = lane * VEC;
  float dc = dis[c];
  float acc[VEC];
  const float* p = X + (size_t)c * C + j;
#pragma unroll
  for (int u = 0; u < VEC; ++u) acc[u] = dc * p[u];
  int s = off[c], e = off[c + 1];
  for (int t = s; t < e; ++t) {
    int sr = srcs[t];
    float ds = dis[sr];
    const float* q = X + (size_t)sr * C + j;
#pragma unroll
    for (int u = 0; u < VEC; ++u) acc[u] += ds * q[u];
  }
#pragma unroll
  for (int u = 0; u < VEC; ++u) buf[w][j + u] = dc * acc[u];
  __syncthreads();
  constexpr int NC = C / 8;
  if (lane < NC) {
    const float* src = &buf[w][lane * 8];
    ushort8 hv, lv;
#pragma unroll
    for (int e2 = 0; e2 < 8; ++e2) {
      unsigned short he, le;
      split2(src[e2], he, le);
      hv[e2] = he; lv[e2] = le;
    }
    size_t ch = pchunk(c, lane * 8, C >> 5);
    *(ushort8*)&h[ch * 8] = hv;
    *(ushort8*)&l[ch * 8] = lv;
  }
}

// X-first spmm (gcn4): out = relu(dis[c]*(sum of pre-scaled rows) + bias)
template <int C>
__global__ __launch_bounds__(256) void spmm_gather_v(const float* __restrict__ Y,
                                                     const int* __restrict__ off,
                                                     const int* __restrict__ srcs,
                                                     const float* __restrict__ dis,
                                                     const float* __restrict__ bias,
                                                     float* __restrict__ out) {
  constexpr int VEC = C / 64;
  int w = threadIdx.x >> 6, lane = threadIdx.x & 63;
  int c = blockIdx.x * 4 + w;
  int j = lane * VEC;
  float acc[VEC];
  const float* p = Y + (size_t)c * C + j;
#pragma unroll
  for (int u = 0; u < VEC; ++u) acc[u] = p[u];
  int s = off[c], e = off[c + 1];
  for (int t = s; t < e; ++t) {
    const float* q = Y + (size_t)srcs[t] * C + j;
#pragma unroll
    for (int u = 0; u < VEC; ++u) acc[u] += q[u];
  }
  float d = dis[c];
  float* o = out + (size_t)c * C + j;
#pragma unroll
  for (int u = 0; u < VEC; ++u) o[u] = fmaxf(d * acc[u] + bias[j + u], 0.0f);
}

// ---------------- combines ----------------

// combine S partials -> packed bf16 hi/lo row-major (for Z = B1^T Xs)
template <int S>
__global__ void ep_zsplit(const float* __restrict__ p, unsigned short* __restrict__ h,
                          unsigned short* __restrict__ l, int M, int N) {
  int t = blockIdx.x * blockDim.x + threadIdx.x;
  int tile = t >> 6, w = t & 63;
  int NT = N >> 5;
  int rt = tile / NT, kt = tile % NT;
  int r = rt * 16 + (w & 15);
  int k = kt * 32 + (w >> 4) * 8;
  const float* p0 = p + (size_t)r * N + k;
  ushort8 hv, lv;
#pragma unroll
  for (int e = 0; e < 8; ++e) {
    float v = p0[e];
#pragma unroll
    for (int s = 1; s < S; ++s) v += p0[(size_t)s * M * N + e];
    unsigned short he, le;
    split2(v, he, le);
    hv[e] = he; lv[e] = le;
  }
  *(ushort8*)&h[(size_t)t * 8] = hv;
  *(ushort8*)&l[(size_t)t * 8] = lv;
}

// unpool + fold split-K epilogue: x = res[r] + (kept? relu(rs*(sum partials)+bias) : 0) -> packed split
template <int S, int RSQ>
__global__ void unpool_ep_split(const float* __restrict__ res, const float* __restrict__ pscr,
                                const int* __restrict__ kept, const float* __restrict__ rs,
                                const float* __restrict__ bias,
                                unsigned short* __restrict__ h, unsigned short* __restrict__ l,
                                int M, int C) {
  int c = blockIdx.x * blockDim.x + threadIdx.x;
  int lane = c & 63, tile = c >> 6;
  int NT = C >> 5;
  int kt = tile % NT, rt = tile / NT;
  int r = rt * 16 + (lane & 15);
  int j0 = kt * 32 + (lane >> 4) * 8;
  int kv = kept[r];
  float rsv = 0.f;
  if (kv >= 0) { rsv = rs[kv]; if (RSQ) rsv = rsqrtf(rsv); }
  ushort8 hv, lv;
#pragma unroll
  for (int e = 0; e < 8; ++e) {
    float v = res[(size_t)r * C + j0 + e];
    if (kv >= 0) {
      float a = 0.f;
#pragma unroll
      for (int s = 0; s < S; ++s) a += pscr[((size_t)s * M + kv) * C + j0 + e];
      v += fmaxf(rsv * a + bias[j0 + e], 0.0f);
    }
    unsigned short he, le;
    split2(v, he, le);
    hv[e] = he; lv[e] = le;
  }
  *(ushort8*)&h[(size_t)c * 8] = hv;
  *(ushort8*)&l[(size_t)c * 8] = lv;
}

// combine S partials (+I) -> PACKED transpose-split B2t directly, + column sums into deg
template <int S>
__global__ void ep_aug_cs2(const float* __restrict__ p, unsigned short* __restrict__ th,
                           unsigned short* __restrict__ tl, float* __restrict__ deg, int n) {
  int c = blockIdx.x * 256 + threadIdx.x;
  int r0 = blockIdx.y * 64;
  int NT = n >> 5;
  float cs = 0.f;
  for (int g = 0; g < 8; ++g) {
    float vbuf[8];
#pragma unroll
    for (int e = 0; e < 8; ++e) {
      int r = r0 + g * 8 + e;
      float v = 0.f;
#pragma unroll
      for (int s = 0; s < S; ++s) v += p[((size_t)s * n + r) * n + c];
      if (r == c) v += 1.0f;
      vbuf[e] = v;
      cs += v;
    }
    ushort8 hv, lv;
#pragma unroll
    for (int e = 0; e < 8; ++e) {
      unsigned short he, le;
      split2(vbuf[e], he, le);
      hv[e] = he; lv[e] = le;
    }
    size_t ch = pchunk(c, r0 + g * 8, NT);
    *(ushort8*)&th[ch * 8] = hv;
    *(ushort8*)&tl[ch * 8] = lv;
  }
  atomicAdd(&deg[c], cs);
}

// ---------------- bf16-split MFMA GEMM, 32x32/wave ----------------
// S>1: partial to C + z*M*N. S==1 EPI: 0 plain; 1 rowscale; 2 rowscale+packed-T-split;
// 3 rowscale+bias+relu; 4 bias+relu. RSQ: rs -> rsqrt(rs).
template <int EPI, int AL, int BL, int KK, int S, int RSQ>
__global__ __launch_bounds__(256) void gemm16(
    const unsigned short* __restrict__ Ah, const unsigned short* __restrict__ Al,
    const unsigned short* __restrict__ Bh, const unsigned short* __restrict__ Bl,
    int M, int N, const float* __restrict__ rs, const float* __restrict__ bias,
    float* __restrict__ C, unsigned short* __restrict__ Th, unsigned short* __restrict__ Tl) {
  static_assert(KK % 32 == 0, "K");
  constexpr int KSTEPS = KK / 32;
  const int NT = (KK * S) >> 5;
  const int gx = gridDim.x;
  int id = blockIdx.y * gx + blockIdx.x;
  int cpx = (gx * gridDim.y) >> 3;
  int sid = (id & 7) * cpx + (id >> 3);
  const int bx = sid % gx, by = sid / gx;
  const int z = (S > 1) ? blockIdx.z : 0;
  const int wid = threadIdx.x >> 6, lane = threadIdx.x & 63;
  const int i0 = by * 64 + (wid >> 1) * 32;
  const int j0 = bx * 64 + (wid & 1) * 32;
  const int lr = lane & 15, lk = lane >> 4;
  size_t aoff[2], boff[2];
#pragma unroll
  for (int t = 0; t < 2; ++t) {
    aoff[t] = ((size_t)((i0 >> 4) + t) * NT + z * (KK >> 5)) * 512 + lane * 8;
    boff[t] = ((size_t)((j0 >> 4) + t) * NT + z * (KK >> 5)) * 512 + lane * 8;
  }
  const f32x4 zf = {0.f, 0.f, 0.f, 0.f};
  f32x4 acc[2][2];
  acc[0][0] = zf; acc[0][1] = zf; acc[1][0] = zf; acc[1][1] = zf;

  bf16x8 ahf[4][2], bhf[4][2], alf[4][2], blf[4][2];
  auto loadk = [&](int kk, int b) {
    size_t o = (size_t)kk * 512;
    ahf[b][0] = *(const bf16x8*)(Ah + aoff[0] + o);
    ahf[b][1] = *(const bf16x8*)(Ah + aoff[1] + o);
    bhf[b][0] = *(const bf16x8*)(Bh + boff[0] + o);
    bhf[b][1] = *(const bf16x8*)(Bh + boff[1] + o);
    if constexpr (AL) {
      alf[b][0] = *(const bf16x8*)(Al + aoff[0] + o);
      alf[b][1] = *(const bf16x8*)(Al + aoff[1] + o);
    }
    if constexpr (BL) {
      blf[b][0] = *(const bf16x8*)(Bl + boff[0] + o);
      blf[b][1] = *(const bf16x8*)(Bl + boff[1] + o);
    }
  };
  auto domm = [&](int b) {
#pragma unroll
    for (int am = 0; am < 2; ++am)
#pragma unroll
      for (int bn = 0; bn < 2; ++bn) {
        acc[am][bn] = __builtin_amdgcn_mfma_f32_16x16x32_bf16(ahf[b][am], bhf[b][bn], acc[am][bn], 0, 0, 0);
        if constexpr (BL)
          acc[am][bn] = __builtin_amdgcn_mfma_f32_16x16x32_bf16(ahf[b][am], blf[b][bn], acc[am][bn], 0, 0, 0);
        if constexpr (AL)
          acc[am][bn] = __builtin_amdgcn_mfma_f32_16x16x32_bf16(alf[b][am], bhf[b][bn], acc[am][bn], 0, 0, 0);
      }
  };

  loadk(0, 0);
  if constexpr (KSTEPS > 1) loadk(1, 1);
  if constexpr (KSTEPS > 2) loadk(2, 2);
#pragma unroll
  for (int kk = 0; kk < KSTEPS; ++kk) {
    const int cur = kk & 3;
    if (kk + 3 < KSTEPS) loadk(kk + 3, (cur + 3) & 3);
    domm(cur);
  }

#pragma unroll
  for (int am = 0; am < 2; ++am)
#pragma unroll
    for (int bn = 0; bn < 2; ++bn) {
      int ib = i0 + 16 * am + lk * 4;
      int j = j0 + 16 * bn + lr;
      f32x4 a = acc[am][bn];
      if constexpr (S > 1) {
#pragma unroll
        for (int r = 0; r < 4; ++r) C[((size_t)z * M + ib + r) * N + j] = a[r];
      } else if constexpr (EPI == 0) {
#pragma unroll
        for (int r = 0; r < 4; ++r) C[(size_t)(ib + r) * N + j] = a[r];
      } else if constexpr (EPI == 1) {
#pragma unroll
        for (int r = 0; r < 4; ++r) {
          float rsv = rs[ib + r];
          if (RSQ) rsv = rsqrtf(rsv);
          C[(size_t)(ib + r) * N + j] = rsv * a[r];
        }
      } else if constexpr (EPI == 2) {
        unsigned long long hp = 0, lp = 0;
#pragma unroll
        for (int r = 0; r < 4; ++r) {
          float rsv = rs[ib + r];
          if (RSQ) rsv = rsqrtf(rsv);
          unsigned short hv, lv;
          split2(rsv * a[r], hv, lv);
          hp |= ((unsigned long long)hv) << (16 * r);
          lp |= ((unsigned long long)lv) << (16 * r);
        }
        size_t c = pchunk(j, ib, M >> 5);
        *(unsigned long long*)&Th[c * 8 + (ib & 7)] = hp;
        *(unsigned long long*)&Tl[c * 8 + (ib & 7)] = lp;
      } else if constexpr (EPI == 3) {
#pragma unroll
        for (int r = 0; r < 4; ++r) {
          float rsv = rs[ib + r];
          if (RSQ) rsv = rsqrtf(rsv);
          C[(size_t)(ib + r) * N + j] = fmaxf(rsv * a[r] + bias[j], 0.0f);
        }
      } else {
#pragma unroll
        for (int r = 0; r < 4; ++r)
          C[(size_t)(ib + r) * N + j] = fmaxf(a[r] + bias[j], 0.0f);
      }
    }
}

// ---------------- bf16-split MFMA GEMM, 64x64/wave (split-K partials) ----------------
template <int AL, int BL, int KK, int S>
__global__ __launch_bounds__(256) void gemm64(
    const unsigned short* __restrict__ Ah, const unsigned short* __restrict__ Al,
    const unsigned short* __restrict__ Bh, const unsigned short* __restrict__ Bl,
    int M, int N, float* __restrict__ C) {
  static_assert(KK % 32 == 0, "K");
  constexpr int KSTEPS = KK / 32;
  const int NT = (KK * S) >> 5;
  const int gx = gridDim.x;
  int id = blockIdx.y * gx + blockIdx.x;
  int cpx = (gx * gridDim.y) >> 3;
  int sid = (id & 7) * cpx + (id >> 3);
  const int bx = sid % gx, by = sid / gx;
  const int z = blockIdx.z;
  const int wid = threadIdx.x >> 6, lane = threadIdx.x & 63;
  const int i0 = by * 128 + (wid >> 1) * 64;
  const int j0 = bx * 128 + (wid & 1) * 64;
  const int lr = lane & 15, lk = lane >> 4;
  size_t aoff[4], boff[4];
#pragma unroll
  for (int t = 0; t < 4; ++t) {
    aoff[t] = ((size_t)((i0 >> 4) + t) * NT + z * (KK >> 5)) * 512 + lane * 8;
    boff[t] = ((size_t)((j0 >> 4) + t) * NT + z * (KK >> 5)) * 512 + lane * 8;
  }
  const f32x4 zf = {0.f, 0.f, 0.f, 0.f};
  f32x4 acc[4][4];
#pragma unroll
  for (int a = 0; a < 4; ++a)
#pragma unroll
    for (int b = 0; b < 4; ++b) acc[a][b] = zf;

  bf16x8 ahf[2][4], bhf[2][4], alf[2][4], blf[2][4];
  auto loadk = [&](int kk, int b) {
    size_t o = (size_t)kk * 512;
#pragma unroll
    for (int t = 0; t < 4; ++t) {
      ahf[b][t] = *(const bf16x8*)(Ah + aoff[t] + o);
      bhf[b][t] = *(const bf16x8*)(Bh + boff[t] + o);
      if constexpr (AL) alf[b][t] = *(const bf16x8*)(Al + aoff[t] + o);
      if constexpr (BL) blf[b][t] = *(const bf16x8*)(Bl + boff[t] + o);
    }
  };
  auto domm = [&](int b) {
#pragma unroll
    for (int am = 0; am < 4; ++am)
#pragma unroll
      for (int bn = 0; bn < 4; ++bn) {
        acc[am][bn] = __builtin_amdgcn_mfma_f32_16x16x32_bf16(ahf[b][am], bhf[b][bn], acc[am][bn], 0, 0, 0);
        if constexpr (BL)
          acc[am][bn] = __builtin_amdgcn_mfma_f32_16x16x32_bf16(ahf[b][am], blf[b][bn], acc[am][bn], 0, 0, 0);
        if constexpr (AL)
          acc[am][bn] = __builtin_amdgcn_mfma_f32_16x16x32_bf16(alf[b][am], bhf[b][bn], acc[am][bn], 0, 0, 0);
      }
  };

  loadk(0, 0);
#pragma unroll
  for (int kk = 0; kk < KSTEPS; ++kk) {
    const int cur = kk & 1;
    if (kk + 1 < KSTEPS) loadk(kk + 1, cur ^ 1);
    domm(cur);
  }

#pragma unroll
  for (int am = 0; am < 4; ++am)
#pragma unroll
    for (int bn = 0; bn < 4; ++bn) {
      int ib = i0 + 16 * am + lk * 4;
      int j = j0 + 16 * bn + lr;
      f32x4 a = acc[am][bn];
#pragma unroll
      for (int r = 0; r < 4; ++r) C[((size_t)z * M + ib + r) * N + j] = a[r];
    }
}

// ---------------- launch ----------------

extern "C" void kernel_launch(void* const* d_in, const int* in_sizes, int n_in,
                              void* d_out, int out_size, void* d_ws, size_t ws_size,
                              hipStream_t stream) {
  (void)in_sizes; (void)n_in; (void)out_size; (void)ws_size;
  const float* x  = (const float*)d_in[0];
  const int* ei   = (const int*)d_in[1];
  const int* esrc = ei;
  const int* edst = ei + EE;
  const float* w0 = (const float*)d_in[2];
  const float* b0 = (const float*)d_in[3];
  const float* w1 = (const float*)d_in[4];
  const float* b1 = (const float*)d_in[5];
  const float* w2 = (const float*)d_in[6];
  const float* b2 = (const float*)d_in[7];
  const float* w3 = (const float*)d_in[8];
  const float* b3 = (const float*)d_in[9];
  const float* w4 = (const float*)d_in[10];
  const float* b4 = (const float*)d_in[11];
  const float* p0 = (const float*)d_in[12];
  const float* p1 = (const float*)d_in[13];
  float* out = (float*)d_out;

  char* ws = (char*)d_ws;
  size_t off = 0;
  auto alloc = [&](size_t b) { void* p = ws + off; off += (b + 255) & ~(size_t)255; return p; };

  int* csc_off = (int*)alloc(4 * (NN + 1));
  int* csr_off = (int*)alloc(4 * (NN + 1));
  int* csc_src = (int*)alloc(4 * EE);
  int* csr_dst = (int*)alloc(4 * EE);

  // zeroed region: 4 count arrays + deg2 + rank0 + rank1
  size_t zero_bytes = 4 * NN * 4 + 4 * NP2 + 4 * NN + 4 * NP1;
  int* cnts    = (int*)alloc(zero_bytes);
  int* cnt_dst = cnts;
  int* cnt_src = cnts + NN;
  int* fill_dst = cnts + 2 * NN;
  int* fill_src = cnts + 3 * NN;
  float* deg2 = (float*)(cnts + 4 * NN);
  int* rank0 = (int*)(deg2 + NP2);
  int* rank1 = rank0 + NN;

  int* cntk  = (int*)alloc(4 * NN);
  int* kept0 = (int*)alloc(4 * NN);
  int* perm0 = (int*)alloc(4 * NP1);
  int* kept1 = (int*)alloc(4 * NP1);
  int* perm1 = (int*)alloc(4 * NP2);
  float* dis0 = (float*)alloc(4 * NN);
  float* dis1 = (float*)alloc(4 * NP1);
  float* pnrm = (float*)alloc(8);
  float* s0   = (float*)alloc(4 * NN);
  float* vals0 = (float*)alloc(4 * NP1);
  float* s1   = (float*)alloc(4 * NP1);
  float* vals1 = (float*)alloc(4 * NP2);
  unsigned long long* keys0 = (unsigned long long*)alloc(8 * NN);
  unsigned long long* keys1 = (unsigned long long*)alloc(8 * NP1);

  const size_t MB = 1024 * 1024;
  // 16MB region: Gh2/Hh2 gathers (0..8MB); later B2t splits (4..8MB, over dead Hh2)
  char* regB1 = (char*)alloc(16 * MB);
  unsigned short* Gh2 = (unsigned short*)regB1;
  unsigned short* Hh2 = (unsigned short*)(regB1 + 4 * MB);
  unsigned short* B2th = (unsigned short*)(regB1 + 4 * MB);
  unsigned short* B2tl = (unsigned short*)(regB1 + 6 * MB);
  float* pscr = (float*)alloc(16 * MB);  // split-K partials

  unsigned short* B1rm = (unsigned short*)alloc(8 * MB);  // packed bf16 (exact)
  unsigned short* B1t  = (unsigned short*)alloc(8 * MB);  // packed bf16 transpose (exact)
  float* res0 = (float*)alloc(4 * MB);
  float* res1 = (float*)alloc(4 * MB);
  float* yreg = (float*)alloc(4 * MB);   // y4 (4096x128)
  char* ytreg = (char*)alloc(4 * MB);    // Y2t h+l / Y3t h+l
  unsigned short* Y2th = (unsigned short*)ytreg;
  unsigned short* Y2tl = (unsigned short*)(ytreg + 1 * MB);
  unsigned short* Y3th = (unsigned short*)ytreg;
  unsigned short* Y3tl = (unsigned short*)(ytreg + 1 * MB);
  char* xsreg = (char*)alloc(4 * MB);    // x3 h+l -> x4 h+l
  unsigned short* x3h = (unsigned short*)xsreg;
  unsigned short* x3l = (unsigned short*)(xsreg + 2 * MB);
  unsigned short* x4h = (unsigned short*)xsreg;
  unsigned short* x4l = (unsigned short*)(xsreg + 2 * MB);
  unsigned short* xh = (unsigned short*)alloc(1 * MB);   // Gh (4096x128 split)
  unsigned short* xl = (unsigned short*)alloc(1 * MB);
  char* xsm = (char*)alloc(2 * MB);      // x1t h+l -> Z h+l -> x2 h+l
  unsigned short* x1th = (unsigned short*)xsm;
  unsigned short* x1tl = (unsigned short*)(xsm + 1 * MB);
  unsigned short* Zh = (unsigned short*)xsm;
  unsigned short* Zl = (unsigned short*)(xsm + 1 * MB);
  unsigned short* x2h = (unsigned short*)xsm;
  unsigned short* x2l = (unsigned short*)(xsm + 1 * MB);
  unsigned short* Wt0h = (unsigned short*)alloc(256 * 128 * 2);
  unsigned short* Wt0l = (unsigned short*)alloc(256 * 128 * 2);
  unsigned short* Wt1h = (unsigned short*)alloc(512 * 256 * 2);
  unsigned short* Wt1l = (unsigned short*)alloc(512 * 256 * 2);
  unsigned short* Wt2h = (unsigned short*)alloc(512 * 512 * 2);
  unsigned short* Wt2l = (unsigned short*)alloc(512 * 512 * 2);
  unsigned short* Wt3h = (unsigned short*)alloc(256 * 512 * 2);
  unsigned short* Wt3l = (unsigned short*)alloc(256 * 512 * 2);
  unsigned short* Wt4h = (unsigned short*)alloc(128 * 256 * 2);
  unsigned short* Wt4l = (unsigned short*)alloc(128 * 256 * 2);

  hipMemsetAsync(cnts, 0, zero_bytes, stream);

  // graph build + weight conversions + p-norms
  prep_all<<<EE / 256 + 288 + 2, 256, 0, stream>>>(
      esrc, edst, cnt_src, cnt_dst, w0, w1, w2, w3, w4,
      Wt0h, Wt0l, Wt1h, Wt1l, Wt2h, Wt2l, Wt3h, Wt3l, Wt4h, Wt4l, p0, p1, pnrm);
  scan2<<<2, 1024, 0, stream>>>(cnt_dst, cnt_src, csc_off, csr_off, dis0, NN);
  scatter_kernel<<<EE / 256, 256, 0, stream>>>(esrc, edst, csc_off, csr_off,
                                               fill_dst, fill_src, csc_src, csr_dst, EE);

  // gcn0 (A-first): G = dis ⊙ (M+I)^T (dis ⊙ x) -> packed split; res0 = relu(G W0 + b0)
  spmm_presplit<128><<<NN / 4, 256, 0, stream>>>(x, csc_off, csc_src, dis0, xh, xl);
  gemm16<4, 1, 1, 128, 1, 0><<<dim3(4, 64), 256, 0, stream>>>(xh, xl, Wt0h, Wt0l,
                                                              NN, 256, nullptr, b0, res0, nullptr, nullptr);

  // pool0
  score_key<<<NN, 256, 0, stream>>>(res0, p0, pnrm + 0, s0, keys0, 256);
  rank_count<<<dim3(NN / 256, NN / 256), 256, 0, stream>>>(keys0, rank0);
  rank_place<<<NN / 256, 256, 0, stream>>>(s0, rank0, NP1, NN, kept0, perm0, vals0, cntk);

  // augment0 (fused): packed B1rm rows + kept-edge counts; then transpose + dis1 (fused)
  augcnt<<<NP1 + EE / 256, 256, 0, stream>>>(csr_off, csr_dst, kept0, perm0, B1rm,
                                             esrc, edst, cntk);
  degtp<<<1024 + NP1 / 4, 256, 0, stream>>>(B1rm, B1t, NP1, csc_off, csc_src, cntk, perm0, dis1);

  // gcn1 (A-first): Z = B1^T (dis1 ⊙ x1); res1 = relu(dis1 ⊙ (Z W1) + b1)
  pool_tsplit_p<<<(NP1 * 256 / 8) / 256, 256, 0, stream>>>(res0, perm0, vals0, dis1, x1th, x1tl);
  gemm64<0, 1, 256, 8><<<dim3(2, 16, 8), 256, 0, stream>>>(B1t, nullptr, x1th, x1tl,
                                                           NP1, 256, pscr);
  ep_zsplit<8><<<(NP1 * 256 / 8) / 256, 256, 0, stream>>>(pscr, Zh, Zl, NP1, 256);
  gemm16<3, 1, 1, 256, 1, 0><<<dim3(8, 32), 256, 0, stream>>>(Zh, Zl, Wt1h, Wt1l,
                                                              NP1, 512, dis1, b1, res1, nullptr, nullptr);

  // pool1
  score_key<<<NP1, 256, 0, stream>>>(res1, p1, pnrm + 1, s1, keys1, 512);
  rank_count<<<dim3(NP1 / 256, NP1 / 256), 256, 0, stream>>>(keys1, rank1);
  rank_place<<<NP1 / 256, 256, 0, stream>>>(s1, rank1, NP2, NP1, kept1, perm1, vals1, nullptr);

  // pool1 pooled-features split + both packed gathers (1 fused launch)
  pool1_misc<<<256 + 2048, 256, 0, stream>>>(res1, perm1, vals1, x2h, x2l,
                                             B1rm, B1t, Gh2, Hh2);

  // augment1: dense exact GEMM (split-K) -> packed B2t + colsums
  gemm64<0, 0, 512, 4><<<dim3(8, 8, 4), 256, 0, stream>>>(Gh2, nullptr, Hh2, nullptr,
                                                          NP2, NP2, pscr);
  ep_aug_cs2<4><<<dim3(NP2 / 256, NP2 / 64), 256, 0, stream>>>(pscr, B2th, B2tl, deg2, NP2);

  // gcn2 (bottleneck, X-first); dis2 = rsqrt(deg2) folded into epilogues
  gemm16<2, 1, 1, 512, 1, 1><<<dim3(8, 16), 256, 0, stream>>>(x2h, x2l, Wt2h, Wt2l,
                                                              NP2, 512, deg2, nullptr, nullptr, Y2th, Y2tl);
  gemm16<0, 1, 1, 512, 2, 0><<<dim3(8, 16, 2), 256, 0, stream>>>(B2th, B2tl, Y2th, Y2tl,
                                                                 NP2, 512, nullptr, nullptr, pscr, nullptr, nullptr);

  // up1: unpool + gcn2-combine folded, emit packed x3
  unpool_ep_split<2, 1><<<(NP1 * 512 / 8) / 256, 256, 0, stream>>>(res1, pscr, kept1, deg2, b2,
                                                                   x3h, x3l, NP2, 512);
  gemm16<2, 1, 1, 512, 1, 0><<<dim3(4, 32), 256, 0, stream>>>(x3h, x3l, Wt3h, Wt3l,
                                                              NP1, 256, dis1, nullptr, nullptr, Y3th, Y3tl);
  gemm64<0, 1, 256, 8><<<dim3(2, 16, 8), 256, 0, stream>>>(B1t, nullptr, Y3th, Y3tl,
                                                           NP1, 256, pscr);

  // up0: unpool + gcn3-combine folded, emit packed x4
  unpool_ep_split<8, 0><<<(NN * 256 / 8) / 256, 256, 0, stream>>>(res0, pscr, kept0, dis1, b3,
                                                                  x4h, x4l, NP1, 256);
  gemm16<1, 1, 1, 256, 1, 0><<<dim3(2, 64), 256, 0, stream>>>(x4h, x4l, Wt4h, Wt4l,
                                                              NN, 128, dis0, nullptr, yreg, nullptr, nullptr);
  spmm_gather_v<128><<<NN / 4, 256, 0, stream>>>(yreg, csc_off, csc_src, dis0, b4, out);
}

// Round 14
// 290.551 us; speedup vs baseline: 1.0757x; 1.0143x over previous
//
#include <hip/hip_runtime.h>

#define NN 4096
#define EE 131072
#define NP1 2048
#define NP2 1024

typedef __attribute__((ext_vector_type(8))) __bf16 bf16x8;
typedef __attribute__((ext_vector_type(4))) float f32x4;
typedef __attribute__((ext_vector_type(8))) unsigned short ushort8;

static __device__ inline unsigned short bfbits(__bf16 b) {
  union { __bf16 x; unsigned short u; } c; c.x = b; return c.u;
}
static __device__ inline void split2(float v, unsigned short& h, unsigned short& l) {
  __bf16 hb = (__bf16)v;
  float hf = (float)hb;
  __bf16 lb = (__bf16)(v - hf);
  h = bfbits(hb); l = bfbits(lb);
}

// Packed fragment layout for [R rows][K k] bf16 (R%16==0, K%32==0):
// 16x32 tile (rt,kt); chunk-in-tile = ((k>>3)&3)*16 + (r&15) == MFMA lane id.
static __device__ inline size_t pchunk(int r, int k, int NT) {
  return ((size_t)(r >> 4) * NT + (k >> 5)) * 64 + (((k >> 3) & 3) << 4) + (r & 15);
}

static __device__ inline void tsplit_body(const float* in, unsigned short* oh, unsigned short* ol,
                                          int R, int C, int c) {
  int lane = c & 63, tile = c >> 6;
  int NT = R >> 5;
  int kt = tile % NT, jt = tile / NT;
  int j = jt * 16 + (lane & 15);
  int k = kt * 32 + (lane >> 4) * 8;
  ushort8 hv, lv;
#pragma unroll
  for (int e = 0; e < 8; ++e) {
    unsigned short he, le;
    split2(in[(size_t)(k + e) * C + j], he, le);
    hv[e] = he; lv[e] = le;
  }
  *(ushort8*)&oh[(size_t)c * 8] = hv;
  *(ushort8*)&ol[(size_t)c * 8] = lv;
}

// ---------------- fused prep: edge histogram + weight conversions + p-norms ----------------

__global__ __launch_bounds__(256) void prep_all(
    const int* __restrict__ esrc, const int* __restrict__ edst,
    int* __restrict__ cnt_src, int* __restrict__ cnt_dst,
    const float* w0, const float* w1, const float* w2, const float* w3, const float* w4,
    unsigned short* o0h, unsigned short* o0l, unsigned short* o1h, unsigned short* o1l,
    unsigned short* o2h, unsigned short* o2l, unsigned short* o3h, unsigned short* o3l,
    unsigned short* o4h, unsigned short* o4l,
    const float* p0, const float* p1, float* pnrm) {
  __shared__ float red[4];
  int b = blockIdx.x;
  int tid = threadIdx.x;
  if (b < EE / 256) {
    int e = b * 256 + tid;
    atomicAdd(&cnt_src[esrc[e]], 1);
    atomicAdd(&cnt_dst[edst[e]], 1);
  } else if (b < EE / 256 + 288) {
    int g = (b - EE / 256) * 256 + tid;
    if (g < 4096)        tsplit_body(w0, o0h, o0l, 128, 256, g);
    else if (g < 20480)  tsplit_body(w1, o1h, o1l, 256, 512, g - 4096);
    else if (g < 53248)  tsplit_body(w2, o2h, o2l, 512, 512, g - 20480);
    else if (g < 69632)  tsplit_body(w3, o3h, o3l, 512, 256, g - 53248);
    else                 tsplit_body(w4, o4h, o4l, 256, 128, g - 69632);
  } else {
    int which = b - (EE / 256 + 288);
    const float* p = which ? p1 : p0;
    int C = which ? 512 : 256;
    float acc = 0.f;
    for (int j = tid; j < C; j += 256) { float v = p[j]; acc += v * v; }
    for (int o = 32; o > 0; o >>= 1) acc += __shfl_down(acc, o);
    if ((tid & 63) == 0) red[tid >> 6] = acc;
    __syncthreads();
    if (tid == 0) pnrm[which] = sqrtf(red[0] + red[1] + red[2] + red[3]);
  }
}

// both exclusive scans in one launch (register-serial + 1024-partial scan); block 0 emits dis0
__global__ __launch_bounds__(1024) void scan2(const int* __restrict__ cnt_dst,
                                              const int* __restrict__ cnt_src,
                                              int* __restrict__ csc_off, int* __restrict__ csr_off,
                                              float* __restrict__ dis0, int n) {
  __shared__ int part[1024];
  const int* in = blockIdx.x ? cnt_src : cnt_dst;
  int* out = blockIdx.x ? csr_off : csc_off;
  int tid = threadIdx.x;
  int base = tid * 4;
  int v[4];
  int s = 0;
#pragma unroll
  for (int e = 0; e < 4; ++e) {
    int x = in[base + e];
    v[e] = x; s += x;
    if (blockIdx.x == 0) dis0[base + e] = rsqrtf((float)x + 1.0f);
  }
  part[tid] = s;
  __syncthreads();
  for (int off2 = 1; off2 < 1024; off2 <<= 1) {
    int t = (tid >= off2) ? part[tid - off2] : 0;
    __syncthreads();
    part[tid] += t;
    __syncthreads();
  }
  int run = part[tid] - s;  // exclusive prefix of this thread's chunk
#pragma unroll
  for (int e = 0; e < 4; ++e) { run += v[e]; out[base + e + 1] = run; }
  if (tid == 0) out[0] = 0;
}

__global__ void scatter_kernel(const int* __restrict__ src, const int* __restrict__ dst,
                               const int* __restrict__ csc_off, const int* __restrict__ csr_off,
                               int* __restrict__ fill_dst, int* __restrict__ fill_src,
                               int* __restrict__ csc_src, int* __restrict__ csr_dst, int E) {
  int e = blockIdx.x * blockDim.x + threadIdx.x;
  if (e < E) {
    int s = src[e], d = dst[e];
    int p = atomicAdd(&fill_dst[d], 1);
    csc_src[csc_off[d] + p] = s;
    int q = atomicAdd(&fill_src[s], 1);
    csr_dst[csr_off[s] + q] = d;
  }
}

// ---------------- scoring / topk ----------------

__global__ void score_key(const float* __restrict__ X, const float* __restrict__ p,
                          const float* __restrict__ pn, float* __restrict__ s,
                          unsigned long long* __restrict__ keys, int C) {
  int i = blockIdx.x;
  int tid = threadIdx.x;
  float acc = 0.f;
  for (int j = tid; j < C; j += 256) acc += X[(size_t)i * C + j] * p[j];
  for (int o = 32; o > 0; o >>= 1) acc += __shfl_down(acc, o);
  __shared__ float red[4];
  if ((tid & 63) == 0) red[tid >> 6] = acc;
  __syncthreads();
  if (tid == 0) {
    float sv = tanhf((red[0] + red[1] + red[2] + red[3]) / pn[0]);
    s[i] = sv;
    unsigned u = __float_as_uint(sv);
    unsigned m = (u & 0x80000000u) ? ~u : (u | 0x80000000u);
    keys[i] = (((unsigned long long)(~m)) << 32) | (unsigned)i;  // desc value, asc index
  }
}

// partial rank: block (bx,by) counts keys[by*256..+256) against candidates [bx*256..+256)
__global__ __launch_bounds__(256) void rank_count(const unsigned long long* __restrict__ keys,
                                                  int* __restrict__ rank) {
  __shared__ unsigned long long kk[256];
  int tid = threadIdx.x;
  int cand = blockIdx.x * 256 + tid;
  int base = blockIdx.y * 256;
  kk[tid] = keys[base + tid];
  __syncthreads();
  unsigned long long kc = keys[cand];
  int c = 0;
#pragma unroll 8
  for (int t = 0; t < 256; ++t) c += (kk[t] < kc) ? 1 : 0;
  atomicAdd(&rank[cand], c);
}

// place by rank; optionally emit cntk (1 if kept) for the sparse-deg path
__global__ void rank_place(const float* __restrict__ s, const int* __restrict__ rank, int k, int n,
                           int* __restrict__ kept, int* __restrict__ perm, float* __restrict__ vals,
                           int* __restrict__ cntk) {
  int i = blockIdx.x * blockDim.x + threadIdx.x;
  if (i < n) {
    int r = rank[i];
    int isk = (r < k) ? 1 : 0;
    if (isk) { perm[r] = i; vals[r] = s[i]; kept[i] = r; }
    else kept[i] = -1;
    if (cntk) cntk[i] = isk;
  }
}

// pool-gather + gate + dis-scale + transpose-split packed ([256 ch][2048 nodes])
__global__ void pool_tsplit_p(const float* __restrict__ X, const int* __restrict__ perm,
                              const float* __restrict__ vals, const float* __restrict__ dis,
                              unsigned short* __restrict__ h, unsigned short* __restrict__ l) {
  int c = blockIdx.x * blockDim.x + threadIdx.x;
  int tile = c >> 6, lno = c & 63;
  int kt = tile & 63, jt = tile >> 6;   // NT = 2048/32 = 64
  int j = jt * 16 + (lno & 15);
  int k0 = kt * 32 + (lno >> 4) * 8;
  ushort8 hv, lv;
#pragma unroll
  for (int e = 0; e < 8; ++e) {
    int node = k0 + e;
    float sc = vals[node] * dis[node];
    float v = X[(size_t)perm[node] * 256 + j] * sc;
    unsigned short he, le;
    split2(v, he, le);
    hv[e] = he; lv[e] = le;
  }
  *(ushort8*)&h[(size_t)c * 8] = hv;
  *(ushort8*)&l[(size_t)c * 8] = lv;
}

// fused pool1 siblings: pooled-row packed split (blocks 0..255) + two packed gathers (256..2303)
__global__ __launch_bounds__(256) void pool1_misc(
    const float* __restrict__ res1, const int* __restrict__ perm1, const float* __restrict__ vals1,
    unsigned short* __restrict__ x2h, unsigned short* __restrict__ x2l,
    const unsigned short* __restrict__ B1rm, const unsigned short* __restrict__ B1t,
    unsigned short* __restrict__ Gh2, unsigned short* __restrict__ Hh2) {
  int b = blockIdx.x;
  int tid = threadIdx.x;
  if (b < 256) {
    int c = b * 256 + tid;                // over NP2*512/8 chunks
    int lane = c & 63, tile = c >> 6;
    int kt = tile & 15, rt = tile >> 4;   // NT = 512/32 = 16
    int r = rt * 16 + (lane & 15);
    int k0 = kt * 32 + (lane >> 4) * 8;
    float v = vals1[r];
    const float* src = res1 + (size_t)perm1[r] * 512 + k0;
    ushort8 hv, lv;
#pragma unroll
    for (int e = 0; e < 8; ++e) {
      unsigned short he, le;
      split2(src[e] * v, he, le);
      hv[e] = he; lv[e] = le;
    }
    *(ushort8*)&x2h[(size_t)c * 8] = hv;
    *(ushort8*)&x2l[(size_t)c * 8] = lv;
  } else {
    int idx = b - 256;
    int mat = idx >> 10;
    int c = (idx & 1023) * 256 + tid;     // over NP2*NP1/8 chunks
    const unsigned short* in = mat ? B1t : B1rm;
    unsigned short* outp = mat ? Hh2 : Gh2;
    const int NT = NP1 >> 5;              // 64
    int lane = c & 63, tile = c >> 6;
    int kt = tile % NT, at = tile / NT;
    int a = at * 16 + (lane & 15);
    int sub = lane >> 4;
    int p = perm1[a];
    size_t sc = ((size_t)(p >> 4) * NT + kt) * 64 + sub * 16 + (p & 15);
    *(ushort8*)&outp[(size_t)c * 8] = *(const ushort8*)&in[sc * 8];
  }
}

// ---------------- augment 0 (fused): sparse 2-path rows + kept-edge counts ----------------

__global__ __launch_bounds__(256) void augcnt(const int* __restrict__ csr_off,
                                              const int* __restrict__ csr_dst,
                                              const int* __restrict__ kept,
                                              const int* __restrict__ perm,
                                              unsigned short* __restrict__ rm,
                                              const int* __restrict__ esrc,
                                              const int* __restrict__ edst,
                                              int* __restrict__ cntk) {
  __shared__ float acc[NP1];
  int b = blockIdx.x;
  if (b < NP1) {
    int ki = b;
    int r = perm[ki];
    for (int t = threadIdx.x; t < NP1; t += 256) acc[t] = 0.f;
    __syncthreads();
    int s = csr_off[r], e = csr_off[r + 1];
    int nm = e - s;
    int wave = threadIdx.x >> 6, lane = threadIdx.x & 63;
    for (int m = wave; m <= nm; m += 4) {
      int k = (m < nm) ? csr_dst[s + m] : r;
      int s2 = csr_off[k], e2 = csr_off[k + 1];
      int n2 = e2 - s2;
      for (int t = lane; t <= n2; t += 64) {
        int j = (t < n2) ? csr_dst[s2 + t] : k;
        int kj = kept[j];
        if (kj >= 0) atomicAdd(&acc[kj], 1.0f);
      }
    }
    __syncthreads();
    if (threadIdx.x == 0) acc[ki] += 1.0f;  // +I on pooled graph
    __syncthreads();
    int tid = threadIdx.x;
    ushort8 hv;
#pragma unroll
    for (int e8 = 0; e8 < 8; ++e8) hv[e8] = bfbits((__bf16)acc[tid * 8 + e8]);
    size_t dst = (((size_t)(ki >> 4)) * 64 + (tid >> 2)) * 64 + (size_t)(tid & 3) * 16 + (ki & 15);
    *(ushort8*)&rm[dst * 8] = hv;
  } else {
    int e = (b - NP1) * 256 + threadIdx.x;
    if (kept[esrc[e]] >= 0) atomicAdd(&cntk[edst[e]], 1);
  }
}

// fused: packed transpose of B1rm (blocks 0..1023) + dis1 from sparse degs (blocks 1024..1535)
__global__ __launch_bounds__(256) void degtp(const unsigned short* __restrict__ in,
                                             unsigned short* __restrict__ outp, int n,
                                             const int* __restrict__ csc_off,
                                             const int* __restrict__ csc_src,
                                             const int* __restrict__ cntk,
                                             const int* __restrict__ perm,
                                             float* __restrict__ dis) {
  __shared__ unsigned short t[64][72];
  int b = blockIdx.x;
  if (b < 1024) {
    int r0 = (b >> 5) * 64, c0 = (b & 31) * 64;
    int NT = n >> 5;
    for (int q = threadIdx.x; q < 512; q += 256) {
      int lt = q >> 6, l = q & 63;
      int rt = lt >> 1, kt2 = lt & 1;
      int r = rt * 16 + (l & 15), k = kt2 * 32 + (l >> 4) * 8;
      ushort8 v = *(const ushort8*)&in[pchunk(r0 + r, c0 + k, NT) * 8];
      *(ushort8*)&t[r][k] = v;
    }
    __syncthreads();
    for (int q = threadIdx.x; q < 512; q += 256) {
      int lt = q >> 6, l = q & 63;
      int jt = lt >> 1, kt2 = lt & 1;
      int j = jt * 16 + (l & 15), k = kt2 * 32 + (l >> 4) * 8;
      ushort8 v;
#pragma unroll
      for (int e = 0; e < 8; ++e) v[e] = t[k + e][j];
      *(ushort8*)&outp[pchunk(c0 + j, r0 + k, NT) * 8] = v;
    }
  } else {
    int bid = b - 1024;
    int wid = threadIdx.x >> 6, lane = threadIdx.x & 63;
    int c = bid * 4 + wid;
    int r = perm[c];
    int s = csc_off[r], e = csc_off[r + 1];
    int sum = 0;
    for (int t2 = s + lane; t2 < e; t2 += 64) sum += cntk[csc_src[t2]];
    for (int o = 32; o > 0; o >>= 1) sum += __shfl_down(sum, o);
    if (lane == 0) dis[c] = rsqrtf((float)(sum + cntk[r] + 1));
  }
}

// ---------------- sparse aggregation ----------------

// A-first spmm fused with packed bf16 split output (gcn0)
template <int C>
__global__ __launch_bounds__(256) void spmm_presplit(const float* __restrict__ X,
                                                     const int* __restrict__ off,
                                                     const int* __restrict__ srcs,
                                                     const float* __restrict__ dis,
                                                     unsigned short* __restrict__ h,
                                                     unsigned short* __restrict__ l) {
  __shared__ float buf[4][C];
  constexpr int VEC = C / 64;
  int w = threadIdx.x >> 6, lane = threadIdx.x & 63;
  int c = blockIdx.x * 4 + w;
  int j = lane * VEC;
  float dc = dis[c];
  float acc[VEC];
  const float* p = X + (size_t)c * C + j;
#pragma unroll
  for (int u = 0; u < VEC; ++u) acc[u] = dc * p[u];
  int s = off[c], e = off[c + 1];
  for (int t = s; t < e; ++t) {
    int sr = srcs[t];
    float ds = dis[sr];
    const float* q = X + (size_t)sr * C + j;
#pragma unroll
    for (int u = 0; u < VEC; ++u) acc[u] += ds * q[u];
  }
#pragma unroll
  for (int u = 0; u < VEC; ++u) buf[w][j + u] = dc * acc[u];
  __syncthreads();
  constexpr int NC = C / 8;
  if (lane < NC) {
    const float* src = &buf[w][lane * 8];
    ushort8 hv, lv;
#pragma unroll
    for (int e2 = 0; e2 < 8; ++e2) {
      unsigned short he, le;
      split2(src[e2], he, le);
      hv[e2] = he; lv[e2] = le;
    }
    size_t ch = pchunk(c, lane * 8, C >> 5);
    *(ushort8*)&h[ch * 8] = hv;
    *(ushort8*)&l[ch * 8] = lv;
  }
}

// X-first spmm (gcn4): out = relu(dis[c]*(sum of pre-scaled rows) + bias)
template <int C>
__global__ __launch_bounds__(256) void spmm_gather_v(const float* __restrict__ Y,
                                                     const int* __restrict__ off,
                                                     const int* __restrict__ srcs,
                                                     const float* __restrict__ dis,
                                                     const float* __restrict__ bias,
                                                     float* __restrict__ out) {
  constexpr int VEC = C / 64;
  int w = threadIdx.x >> 6, lane = threadIdx.x & 63;
  int c = blockIdx.x * 4 + w;
  int j = lane * VEC;
  float acc[VEC];
  const float* p = Y + (size_t)c * C + j;
#pragma unroll
  for (int u = 0; u < VEC; ++u) acc[u] = p[u];
  int s = off[c], e = off[c + 1];
  for (int t = s; t < e; ++t) {
    const float* q = Y + (size_t)srcs[t] * C + j;
#pragma unroll
    for (int u = 0; u < VEC; ++u) acc[u] += q[u];
  }
  float d = dis[c];
  float* o = out + (size_t)c * C + j;
#pragma unroll
  for (int u = 0; u < VEC; ++u) o[u] = fmaxf(d * acc[u] + bias[j + u], 0.0f);
}

// ---------------- combines ----------------

// combine S partials -> packed bf16 hi/lo row-major (for Z = B1^T Xs)
template <int S>
__global__ void ep_zsplit(const float* __restrict__ p, unsigned short* __restrict__ h,
                          unsigned short* __restrict__ l, int M, int N) {
  int t = blockIdx.x * blockDim.x + threadIdx.x;
  int tile = t >> 6, w = t & 63;
  int NT = N >> 5;
  int rt = tile / NT, kt = tile % NT;
  int r = rt * 16 + (w & 15);
  int k = kt * 32 + (w >> 4) * 8;
  const float* p0 = p + (size_t)r * N + k;
  ushort8 hv, lv;
#pragma unroll
  for (int e = 0; e < 8; ++e) {
    float v = p0[e];
#pragma unroll
    for (int s = 1; s < S; ++s) v += p0[(size_t)s * M * N + e];
    unsigned short he, le;
    split2(v, he, le);
    hv[e] = he; lv[e] = le;
  }
  *(ushort8*)&h[(size_t)t * 8] = hv;
  *(ushort8*)&l[(size_t)t * 8] = lv;
}

// unpool + fold split-K epilogue: x = res[r] + (kept? relu(rs*(sum partials)+bias) : 0) -> packed split
template <int S, int RSQ>
__global__ void unpool_ep_split(const float* __restrict__ res, const float* __restrict__ pscr,
                                const int* __restrict__ kept, const float* __restrict__ rs,
                                const float* __restrict__ bias,
                                unsigned short* __restrict__ h, unsigned short* __restrict__ l,
                                int M, int C) {
  int c = blockIdx.x * blockDim.x + threadIdx.x;
  int lane = c & 63, tile = c >> 6;
  int NT = C >> 5;
  int kt = tile % NT, rt = tile / NT;
  int r = rt * 16 + (lane & 15);
  int j0 = kt * 32 + (lane >> 4) * 8;
  int kv = kept[r];
  float rsv = 0.f;
  if (kv >= 0) { rsv = rs[kv]; if (RSQ) rsv = rsqrtf(rsv); }
  ushort8 hv, lv;
#pragma unroll
  for (int e = 0; e < 8; ++e) {
    float v = res[(size_t)r * C + j0 + e];
    if (kv >= 0) {
      float a = 0.f;
#pragma unroll
      for (int s = 0; s < S; ++s) a += pscr[((size_t)s * M + kv) * C + j0 + e];
      v += fmaxf(rsv * a + bias[j0 + e], 0.0f);
    }
    unsigned short he, le;
    split2(v, he, le);
    hv[e] = he; lv[e] = le;
  }
  *(ushort8*)&h[(size_t)c * 8] = hv;
  *(ushort8*)&l[(size_t)c * 8] = lv;
}

// combine S partials (+I) -> PACKED transpose-split B2t directly, + column sums into deg
template <int S>
__global__ void ep_aug_cs2(const float* __restrict__ p, unsigned short* __restrict__ th,
                           unsigned short* __restrict__ tl, float* __restrict__ deg, int n) {
  int c = blockIdx.x * 256 + threadIdx.x;
  int r0 = blockIdx.y * 64;
  int NT = n >> 5;
  float cs = 0.f;
  for (int g = 0; g < 8; ++g) {
    float vbuf[8];
#pragma unroll
    for (int e = 0; e < 8; ++e) {
      int r = r0 + g * 8 + e;
      float v = 0.f;
#pragma unroll
      for (int s = 0; s < S; ++s) v += p[((size_t)s * n + r) * n + c];
      if (r == c) v += 1.0f;
      vbuf[e] = v;
      cs += v;
    }
    ushort8 hv, lv;
#pragma unroll
    for (int e = 0; e < 8; ++e) {
      unsigned short he, le;
      split2(vbuf[e], he, le);
      hv[e] = he; lv[e] = le;
    }
    size_t ch = pchunk(c, r0 + g * 8, NT);
    *(ushort8*)&th[ch * 8] = hv;
    *(ushort8*)&tl[ch * 8] = lv;
  }
  atomicAdd(&deg[c], cs);
}

// ---------------- shared GEMM epilogue ----------------
template <int EPI, int S, int RSQ>
static __device__ inline void gemm_epi(f32x4 a, int z, int ib, int j, int M, int N,
                                       const float* rs, const float* bias,
                                       float* C, unsigned short* Th, unsigned short* Tl) {
  if constexpr (S > 1) {
#pragma unroll
    for (int r = 0; r < 4; ++r) C[((size_t)z * M + ib + r) * N + j] = a[r];
  } else if constexpr (EPI == 0) {
#pragma unroll
    for (int r = 0; r < 4; ++r) C[(size_t)(ib + r) * N + j] = a[r];
  } else if constexpr (EPI == 1) {
#pragma unroll
    for (int r = 0; r < 4; ++r) {
      float rsv = rs[ib + r];
      if (RSQ) rsv = rsqrtf(rsv);
      C[(size_t)(ib + r) * N + j] = rsv * a[r];
    }
  } else if constexpr (EPI == 2) {
    unsigned long long hp = 0, lp = 0;
#pragma unroll
    for (int r = 0; r < 4; ++r) {
      float rsv = rs[ib + r];
      if (RSQ) rsv = rsqrtf(rsv);
      unsigned short hv, lv;
      split2(rsv * a[r], hv, lv);
      hp |= ((unsigned long long)hv) << (16 * r);
      lp |= ((unsigned long long)lv) << (16 * r);
    }
    size_t c = pchunk(j, ib, M >> 5);
    *(unsigned long long*)&Th[c * 8 + (ib & 7)] = hp;
    *(unsigned long long*)&Tl[c * 8 + (ib & 7)] = lp;
  } else if constexpr (EPI == 3) {
#pragma unroll
    for (int r = 0; r < 4; ++r) {
      float rsv = rs[ib + r];
      if (RSQ) rsv = rsqrtf(rsv);
      C[(size_t)(ib + r) * N + j] = fmaxf(rsv * a[r] + bias[j], 0.0f);
    }
  } else {
#pragma unroll
    for (int r = 0; r < 4; ++r)
      C[(size_t)(ib + r) * N + j] = fmaxf(a[r] + bias[j], 0.0f);
  }
}

// ---------------- bf16-split MFMA GEMM, 32x32/wave, 4 waves (64x64 tile) ----------------
template <int EPI, int AL, int BL, int KK, int S, int RSQ>
__global__ __launch_bounds__(256) void gemm16(
    const unsigned short* __restrict__ Ah, const unsigned short* __restrict__ Al,
    const unsigned short* __restrict__ Bh, const unsigned short* __restrict__ Bl,
    int M, int N, const float* __restrict__ rs, const float* __restrict__ bias,
    float* __restrict__ C, unsigned short* __restrict__ Th, unsigned short* __restrict__ Tl) {
  static_assert(KK % 32 == 0, "K");
  constexpr int KSTEPS = KK / 32;
  const int NT = (KK * S) >> 5;
  const int gx = gridDim.x;
  int id = blockIdx.y * gx + blockIdx.x;
  int cpx = (gx * gridDim.y) >> 3;
  int sid = (id & 7) * cpx + (id >> 3);
  const int bx = sid % gx, by = sid / gx;
  const int z = (S > 1) ? blockIdx.z : 0;
  const int wid = threadIdx.x >> 6, lane = threadIdx.x & 63;
  const int i0 = by * 64 + (wid >> 1) * 32;
  const int j0 = bx * 64 + (wid & 1) * 32;
  const int lr = lane & 15, lk = lane >> 4;
  size_t aoff[2], boff[2];
#pragma unroll
  for (int t = 0; t < 2; ++t) {
    aoff[t] = ((size_t)((i0 >> 4) + t) * NT + z * (KK >> 5)) * 512 + lane * 8;
    boff[t] = ((size_t)((j0 >> 4) + t) * NT + z * (KK >> 5)) * 512 + lane * 8;
  }
  const f32x4 zf = {0.f, 0.f, 0.f, 0.f};
  f32x4 acc[2][2];
  acc[0][0] = zf; acc[0][1] = zf; acc[1][0] = zf; acc[1][1] = zf;

  bf16x8 ahf[4][2], bhf[4][2], alf[4][2], blf[4][2];
  auto loadk = [&](int kk, int b) {
    size_t o = (size_t)kk * 512;
    ahf[b][0] = *(const bf16x8*)(Ah + aoff[0] + o);
    ahf[b][1] = *(const bf16x8*)(Ah + aoff[1] + o);
    bhf[b][0] = *(const bf16x8*)(Bh + boff[0] + o);
    bhf[b][1] = *(const bf16x8*)(Bh + boff[1] + o);
    if constexpr (AL) {
      alf[b][0] = *(const bf16x8*)(Al + aoff[0] + o);
      alf[b][1] = *(const bf16x8*)(Al + aoff[1] + o);
    }
    if constexpr (BL) {
      blf[b][0] = *(const bf16x8*)(Bl + boff[0] + o);
      blf[b][1] = *(const bf16x8*)(Bl + boff[1] + o);
    }
  };
  auto domm = [&](int b) {
#pragma unroll
    for (int am = 0; am < 2; ++am)
#pragma unroll
      for (int bn = 0; bn < 2; ++bn) {
        acc[am][bn] = __builtin_amdgcn_mfma_f32_16x16x32_bf16(ahf[b][am], bhf[b][bn], acc[am][bn], 0, 0, 0);
        if constexpr (BL)
          acc[am][bn] = __builtin_amdgcn_mfma_f32_16x16x32_bf16(ahf[b][am], blf[b][bn], acc[am][bn], 0, 0, 0);
        if constexpr (AL)
          acc[am][bn] = __builtin_amdgcn_mfma_f32_16x16x32_bf16(alf[b][am], bhf[b][bn], acc[am][bn], 0, 0, 0);
      }
  };

  loadk(0, 0);
  if constexpr (KSTEPS > 1) loadk(1, 1);
  if constexpr (KSTEPS > 2) loadk(2, 2);
#pragma unroll
  for (int kk = 0; kk < KSTEPS; ++kk) {
    const int cur = kk & 3;
    if (kk + 3 < KSTEPS) loadk(kk + 3, (cur + 3) & 3);
    domm(cur);
  }

#pragma unroll
  for (int am = 0; am < 2; ++am)
#pragma unroll
    for (int bn = 0; bn < 2; ++bn)
      gemm_epi<EPI, S, RSQ>(acc[am][bn], z, i0 + 16 * am + lk * 4, j0 + 16 * bn + lr,
                            M, N, rs, bias, C, Th, Tl);
}

// ---------------- bf16-split MFMA GEMM, 32x32/wave, 2 waves (64x32 tile) ----------------
// For small under-occupied GEMMs: doubles block count vs gemm16.
template <int EPI, int AL, int BL, int KK, int S, int RSQ>
__global__ __launch_bounds__(128) void gemm8(
    const unsigned short* __restrict__ Ah, const unsigned short* __restrict__ Al,
    const unsigned short* __restrict__ Bh, const unsigned short* __restrict__ Bl,
    int M, int N, const float* __restrict__ rs, const float* __restrict__ bias,
    float* __restrict__ C, unsigned short* __restrict__ Th, unsigned short* __restrict__ Tl) {
  static_assert(KK % 32 == 0, "K");
  constexpr int KSTEPS = KK / 32;
  const int NT = (KK * S) >> 5;
  const int gx = gridDim.x;
  int id = blockIdx.y * gx + blockIdx.x;
  int cpx = (gx * gridDim.y) >> 3;
  int sid = (id & 7) * cpx + (id >> 3);
  const int bx = sid % gx, by = sid / gx;
  const int z = (S > 1) ? blockIdx.z : 0;
  const int wid = threadIdx.x >> 6, lane = threadIdx.x & 63;
  const int i0 = by * 64 + wid * 32;   // 2 waves stacked on M
  const int j0 = bx * 32;
  const int lr = lane & 15, lk = lane >> 4;
  size_t aoff[2], boff[2];
#pragma unroll
  for (int t = 0; t < 2; ++t) {
    aoff[t] = ((size_t)((i0 >> 4) + t) * NT + z * (KK >> 5)) * 512 + lane * 8;
    boff[t] = ((size_t)((j0 >> 4) + t) * NT + z * (KK >> 5)) * 512 + lane * 8;
  }
  const f32x4 zf = {0.f, 0.f, 0.f, 0.f};
  f32x4 acc[2][2];
  acc[0][0] = zf; acc[0][1] = zf; acc[1][0] = zf; acc[1][1] = zf;

  bf16x8 ahf[4][2], bhf[4][2], alf[4][2], blf[4][2];
  auto loadk = [&](int kk, int b) {
    size_t o = (size_t)kk * 512;
    ahf[b][0] = *(const bf16x8*)(Ah + aoff[0] + o);
    ahf[b][1] = *(const bf16x8*)(Ah + aoff[1] + o);
    bhf[b][0] = *(const bf16x8*)(Bh + boff[0] + o);
    bhf[b][1] = *(const bf16x8*)(Bh + boff[1] + o);
    if constexpr (AL) {
      alf[b][0] = *(const bf16x8*)(Al + aoff[0] + o);
      alf[b][1] = *(const bf16x8*)(Al + aoff[1] + o);
    }
    if constexpr (BL) {
      blf[b][0] = *(const bf16x8*)(Bl + boff[0] + o);
      blf[b][1] = *(const bf16x8*)(Bl + boff[1] + o);
    }
  };
  auto domm = [&](int b) {
#pragma unroll
    for (int am = 0; am < 2; ++am)
#pragma unroll
      for (int bn = 0; bn < 2; ++bn) {
        acc[am][bn] = __builtin_amdgcn_mfma_f32_16x16x32_bf16(ahf[b][am], bhf[b][bn], acc[am][bn], 0, 0, 0);
        if constexpr (BL)
          acc[am][bn] = __builtin_amdgcn_mfma_f32_16x16x32_bf16(ahf[b][am], blf[b][bn], acc[am][bn], 0, 0, 0);
        if constexpr (AL)
          acc[am][bn] = __builtin_amdgcn_mfma_f32_16x16x32_bf16(alf[b][am], bhf[b][bn], acc[am][bn], 0, 0, 0);
      }
  };

  loadk(0, 0);
  if constexpr (KSTEPS > 1) loadk(1, 1);
  if constexpr (KSTEPS > 2) loadk(2, 2);
#pragma unroll
  for (int kk = 0; kk < KSTEPS; ++kk) {
    const int cur = kk & 3;
    if (kk + 3 < KSTEPS) loadk(kk + 3, (cur + 3) & 3);
    domm(cur);
  }

#pragma unroll
  for (int am = 0; am < 2; ++am)
#pragma unroll
    for (int bn = 0; bn < 2; ++bn)
      gemm_epi<EPI, S, RSQ>(acc[am][bn], z, i0 + 16 * am + lk * 4, j0 + 16 * bn + lr,
                            M, N, rs, bias, C, Th, Tl);
}

// ---------------- bf16-split MFMA GEMM, 64x64/wave (split-K partials) ----------------
template <int AL, int BL, int KK, int S>
__global__ __launch_bounds__(256) void gemm64(
    const unsigned short* __restrict__ Ah, const unsigned short* __restrict__ Al,
    const unsigned short* __restrict__ Bh, const unsigned short* __restrict__ Bl,
    int M, int N, float* __restrict__ C) {
  static_assert(KK % 32 == 0, "K");
  constexpr int KSTEPS = KK / 32;
  const int NT = (KK * S) >> 5;
  const int gx = gridDim.x;
  int id = blockIdx.y * gx + blockIdx.x;
  int cpx = (gx * gridDim.y) >> 3;
  int sid = (id & 7) * cpx + (id >> 3);
  const int bx = sid % gx, by = sid / gx;
  const int z = blockIdx.z;
  const int wid = threadIdx.x >> 6, lane = threadIdx.x & 63;
  const int i0 = by * 128 + (wid >> 1) * 64;
  const int j0 = bx * 128 + (wid & 1) * 64;
  const int lr = lane & 15, lk = lane >> 4;
  size_t aoff[4], boff[4];
#pragma unroll
  for (int t = 0; t < 4; ++t) {
    aoff[t] = ((size_t)((i0 >> 4) + t) * NT + z * (KK >> 5)) * 512 + lane * 8;
    boff[t] = ((size_t)((j0 >> 4) + t) * NT + z * (KK >> 5)) * 512 + lane * 8;
  }
  const f32x4 zf = {0.f, 0.f, 0.f, 0.f};
  f32x4 acc[4][4];
#pragma unroll
  for (int a = 0; a < 4; ++a)
#pragma unroll
    for (int b = 0; b < 4; ++b) acc[a][b] = zf;

  bf16x8 ahf[2][4], bhf[2][4], alf[2][4], blf[2][4];
  auto loadk = [&](int kk, int b) {
    size_t o = (size_t)kk * 512;
#pragma unroll
    for (int t = 0; t < 4; ++t) {
      ahf[b][t] = *(const bf16x8*)(Ah + aoff[t] + o);
      bhf[b][t] = *(const bf16x8*)(Bh + boff[t] + o);
      if constexpr (AL) alf[b][t] = *(const bf16x8*)(Al + aoff[t] + o);
      if constexpr (BL) blf[b][t] = *(const bf16x8*)(Bl + boff[t] + o);
    }
  };
  auto domm = [&](int b) {
#pragma unroll
    for (int am = 0; am < 4; ++am)
#pragma unroll
      for (int bn = 0; bn < 4; ++bn) {
        acc[am][bn] = __builtin_amdgcn_mfma_f32_16x16x32_bf16(ahf[b][am], bhf[b][bn], acc[am][bn], 0, 0, 0);
        if constexpr (BL)
          acc[am][bn] = __builtin_amdgcn_mfma_f32_16x16x32_bf16(ahf[b][am], blf[b][bn], acc[am][bn], 0, 0, 0);
        if constexpr (AL)
          acc[am][bn] = __builtin_amdgcn_mfma_f32_16x16x32_bf16(alf[b][am], bhf[b][bn], acc[am][bn], 0, 0, 0);
      }
  };

  loadk(0, 0);
#pragma unroll
  for (int kk = 0; kk < KSTEPS; ++kk) {
    const int cur = kk & 1;
    if (kk + 1 < KSTEPS) loadk(kk + 1, cur ^ 1);
    domm(cur);
  }

#pragma unroll
  for (int am = 0; am < 4; ++am)
#pragma unroll
    for (int bn = 0; bn < 4; ++bn) {
      int ib = i0 + 16 * am + lk * 4;
      int j = j0 + 16 * bn + lr;
      f32x4 a = acc[am][bn];
#pragma unroll
      for (int r = 0; r < 4; ++r) C[((size_t)z * M + ib + r) * N + j] = a[r];
    }
}

// ---------------- launch ----------------

extern "C" void kernel_launch(void* const* d_in, const int* in_sizes, int n_in,
                              void* d_out, int out_size, void* d_ws, size_t ws_size,
                              hipStream_t stream) {
  (void)in_sizes; (void)n_in; (void)out_size; (void)ws_size;
  const float* x  = (const float*)d_in[0];
  const int* ei   = (const int*)d_in[1];
  const int* esrc = ei;
  const int* edst = ei + EE;
  const float* w0 = (const float*)d_in[2];
  const float* b0 = (const float*)d_in[3];
  const float* w1 = (const float*)d_in[4];
  const float* b1 = (const float*)d_in[5];
  const float* w2 = (const float*)d_in[6];
  const float* b2 = (const float*)d_in[7];
  const float* w3 = (const float*)d_in[8];
  const float* b3 = (const float*)d_in[9];
  const float* w4 = (const float*)d_in[10];
  const float* b4 = (const float*)d_in[11];
  const float* p0 = (const float*)d_in[12];
  const float* p1 = (const float*)d_in[13];
  float* out = (float*)d_out;

  char* ws = (char*)d_ws;
  size_t off = 0;
  auto alloc = [&](size_t b) { void* p = ws + off; off += (b + 255) & ~(size_t)255; return p; };

  int* csc_off = (int*)alloc(4 * (NN + 1));
  int* csr_off = (int*)alloc(4 * (NN + 1));
  int* csc_src = (int*)alloc(4 * EE);
  int* csr_dst = (int*)alloc(4 * EE);

  // zeroed region: 4 count arrays + deg2 + rank0 + rank1
  size_t zero_bytes = 4 * NN * 4 + 4 * NP2 + 4 * NN + 4 * NP1;
  int* cnts    = (int*)alloc(zero_bytes);
  int* cnt_dst = cnts;
  int* cnt_src = cnts + NN;
  int* fill_dst = cnts + 2 * NN;
  int* fill_src = cnts + 3 * NN;
  float* deg2 = (float*)(cnts + 4 * NN);
  int* rank0 = (int*)(deg2 + NP2);
  int* rank1 = rank0 + NN;

  int* cntk  = (int*)alloc(4 * NN);
  int* kept0 = (int*)alloc(4 * NN);
  int* perm0 = (int*)alloc(4 * NP1);
  int* kept1 = (int*)alloc(4 * NP1);
  int* perm1 = (int*)alloc(4 * NP2);
  float* dis0 = (float*)alloc(4 * NN);
  float* dis1 = (float*)alloc(4 * NP1);
  float* pnrm = (float*)alloc(8);
  float* s0   = (float*)alloc(4 * NN);
  float* vals0 = (float*)alloc(4 * NP1);
  float* s1   = (float*)alloc(4 * NP1);
  float* vals1 = (float*)alloc(4 * NP2);
  unsigned long long* keys0 = (unsigned long long*)alloc(8 * NN);
  unsigned long long* keys1 = (unsigned long long*)alloc(8 * NP1);

  const size_t MB = 1024 * 1024;
  // 16MB region: Gh2/Hh2 gathers (0..8MB); later B2t splits (4..8MB, over dead Hh2)
  char* regB1 = (char*)alloc(16 * MB);
  unsigned short* Gh2 = (unsigned short*)regB1;
  unsigned short* Hh2 = (unsigned short*)(regB1 + 4 * MB);
  unsigned short* B2th = (unsigned short*)(regB1 + 4 * MB);
  unsigned short* B2tl = (unsigned short*)(regB1 + 6 * MB);
  float* pscr = (float*)alloc(16 * MB);  // split-K partials

  unsigned short* B1rm = (unsigned short*)alloc(8 * MB);  // packed bf16 (exact)
  unsigned short* B1t  = (unsigned short*)alloc(8 * MB);  // packed bf16 transpose (exact)
  float* res0 = (float*)alloc(4 * MB);
  float* res1 = (float*)alloc(4 * MB);
  float* yreg = (float*)alloc(4 * MB);   // y4 (4096x128)
  char* ytreg = (char*)alloc(4 * MB);    // Y2t h+l / Y3t h+l
  unsigned short* Y2th = (unsigned short*)ytreg;
  unsigned short* Y2tl = (unsigned short*)(ytreg + 1 * MB);
  unsigned short* Y3th = (unsigned short*)ytreg;
  unsigned short* Y3tl = (unsigned short*)(ytreg + 1 * MB);
  char* xsreg = (char*)alloc(4 * MB);    // x3 h+l -> x4 h+l
  unsigned short* x3h = (unsigned short*)xsreg;
  unsigned short* x3l = (unsigned short*)(xsreg + 2 * MB);
  unsigned short* x4h = (unsigned short*)xsreg;
  unsigned short* x4l = (unsigned short*)(xsreg + 2 * MB);
  unsigned short* xh = (unsigned short*)alloc(1 * MB);   // Gh (4096x128 split)
  unsigned short* xl = (unsigned short*)alloc(1 * MB);
  char* xsm = (char*)alloc(2 * MB);      // x1t h+l -> Z h+l -> x2 h+l
  unsigned short* x1th = (unsigned short*)xsm;
  unsigned short* x1tl = (unsigned short*)(xsm + 1 * MB);
  unsigned short* Zh = (unsigned short*)xsm;
  unsigned short* Zl = (unsigned short*)(xsm + 1 * MB);
  unsigned short* x2h = (unsigned short*)xsm;
  unsigned short* x2l = (unsigned short*)(xsm + 1 * MB);
  unsigned short* Wt0h = (unsigned short*)alloc(256 * 128 * 2);
  unsigned short* Wt0l = (unsigned short*)alloc(256 * 128 * 2);
  unsigned short* Wt1h = (unsigned short*)alloc(512 * 256 * 2);
  unsigned short* Wt1l = (unsigned short*)alloc(512 * 256 * 2);
  unsigned short* Wt2h = (unsigned short*)alloc(512 * 512 * 2);
  unsigned short* Wt2l = (unsigned short*)alloc(512 * 512 * 2);
  unsigned short* Wt3h = (unsigned short*)alloc(256 * 512 * 2);
  unsigned short* Wt3l = (unsigned short*)alloc(256 * 512 * 2);
  unsigned short* Wt4h = (unsigned short*)alloc(128 * 256 * 2);
  unsigned short* Wt4l = (unsigned short*)alloc(128 * 256 * 2);

  hipMemsetAsync(cnts, 0, zero_bytes, stream);

  // graph build + weight conversions + p-norms
  prep_all<<<EE / 256 + 288 + 2, 256, 0, stream>>>(
      esrc, edst, cnt_src, cnt_dst, w0, w1, w2, w3, w4,
      Wt0h, Wt0l, Wt1h, Wt1l, Wt2h, Wt2l, Wt3h, Wt3l, Wt4h, Wt4l, p0, p1, pnrm);
  scan2<<<2, 1024, 0, stream>>>(cnt_dst, cnt_src, csc_off, csr_off, dis0, NN);
  scatter_kernel<<<EE / 256, 256, 0, stream>>>(esrc, edst, csc_off, csr_off,
                                               fill_dst, fill_src, csc_src, csr_dst, EE);

  // gcn0 (A-first): G = dis ⊙ (M+I)^T (dis ⊙ x) -> packed split; res0 = relu(G W0 + b0)
  spmm_presplit<128><<<NN / 4, 256, 0, stream>>>(x, csc_off, csc_src, dis0, xh, xl);
  gemm16<4, 1, 1, 128, 1, 0><<<dim3(4, 64), 256, 0, stream>>>(xh, xl, Wt0h, Wt0l,
                                                              NN, 256, nullptr, b0, res0, nullptr, nullptr);

  // pool0
  score_key<<<NN, 256, 0, stream>>>(res0, p0, pnrm + 0, s0, keys0, 256);
  rank_count<<<dim3(NN / 256, NN / 256), 256, 0, stream>>>(keys0, rank0);
  rank_place<<<NN / 256, 256, 0, stream>>>(s0, rank0, NP1, NN, kept0, perm0, vals0, cntk);

  // augment0 (fused): packed B1rm rows + kept-edge counts; then transpose + dis1 (fused)
  augcnt<<<NP1 + EE / 256, 256, 0, stream>>>(csr_off, csr_dst, kept0, perm0, B1rm,
                                             esrc, edst, cntk);
  degtp<<<1024 + NP1 / 4, 256, 0, stream>>>(B1rm, B1t, NP1, csc_off, csc_src, cntk, perm0, dis1);

  // gcn1 (A-first): Z = B1^T (dis1 ⊙ x1); res1 = relu(dis1 ⊙ (Z W1) + b1)
  pool_tsplit_p<<<(NP1 * 256 / 8) / 256, 256, 0, stream>>>(res0, perm0, vals0, dis1, x1th, x1tl);
  gemm64<0, 1, 256, 8><<<dim3(2, 16, 8), 256, 0, stream>>>(B1t, nullptr, x1th, x1tl,
                                                           NP1, 256, pscr);
  ep_zsplit<8><<<(NP1 * 256 / 8) / 256, 256, 0, stream>>>(pscr, Zh, Zl, NP1, 256);
  gemm16<3, 1, 1, 256, 1, 0><<<dim3(8, 32), 256, 0, stream>>>(Zh, Zl, Wt1h, Wt1l,
                                                              NP1, 512, dis1, b1, res1, nullptr, nullptr);

  // pool1
  score_key<<<NP1, 256, 0, stream>>>(res1, p1, pnrm + 1, s1, keys1, 512);
  rank_count<<<dim3(NP1 / 256, NP1 / 256), 256, 0, stream>>>(keys1, rank1);
  rank_place<<<NP1 / 256, 256, 0, stream>>>(s1, rank1, NP2, NP1, kept1, perm1, vals1, nullptr);

  // pool1 pooled-features split + both packed gathers (1 fused launch)
  pool1_misc<<<256 + 2048, 256, 0, stream>>>(res1, perm1, vals1, x2h, x2l,
                                             B1rm, B1t, Gh2, Hh2);

  // augment1: dense exact GEMM (split-K) -> packed B2t + colsums
  gemm64<0, 0, 512, 4><<<dim3(8, 8, 4), 256, 0, stream>>>(Gh2, nullptr, Hh2, nullptr,
                                                          NP2, NP2, pscr);
  ep_aug_cs2<4><<<dim3(NP2 / 256, NP2 / 64), 256, 0, stream>>>(pscr, B2th, B2tl, deg2, NP2);

  // gcn2 (bottleneck, X-first); dis2 = rsqrt(deg2) folded into epilogues
  gemm8<2, 1, 1, 512, 1, 1><<<dim3(16, 16), 128, 0, stream>>>(x2h, x2l, Wt2h, Wt2l,
                                                              NP2, 512, deg2, nullptr, nullptr, Y2th, Y2tl);
  gemm16<0, 1, 1, 512, 2, 0><<<dim3(8, 16, 2), 256, 0, stream>>>(B2th, B2tl, Y2th, Y2tl,
                                                                 NP2, 512, nullptr, nullptr, pscr, nullptr, nullptr);

  // up1: unpool + gcn2-combine folded, emit packed x3
  unpool_ep_split<2, 1><<<(NP1 * 512 / 8) / 256, 256, 0, stream>>>(res1, pscr, kept1, deg2, b2,
                                                                   x3h, x3l, NP2, 512);
  gemm8<2, 1, 1, 512, 1, 0><<<dim3(8, 32), 128, 0, stream>>>(x3h, x3l, Wt3h, Wt3l,
                                                             NP1, 256, dis1, nullptr, nullptr, Y3th, Y3tl);
  gemm64<0, 1, 256, 8><<<dim3(2, 16, 8), 256, 0, stream>>>(B1t, nullptr, Y3th, Y3tl,
                                                           NP1, 256, pscr);

  // up0: unpool + gcn3-combine folded, emit packed x4
  unpool_ep_split<8, 0><<<(NN * 256 / 8) / 256, 256, 0, stream>>>(res0, pscr, kept0, dis1, b3,
                                                                  x4h, x4l, NP1, 256);
  gemm8<1, 1, 1, 256, 1, 0><<<dim3(4, 64), 128, 0, stream>>>(x4h, x4l, Wt4h, Wt4l,
                                                             NN, 128, dis0, nullptr, yreg, nullptr, nullptr);
  spmm_gather_v<128><<<NN / 4, 256, 0, stream>>>(yreg, csc_off, csc_src, dis0, b4, out);
}

// Round 15
// 287.983 us; speedup vs baseline: 1.0853x; 1.0089x over previous
//
#include <hip/hip_runtime.h>

#define NN 4096
#define EE 131072
#define NP1 2048
#define NP2 1024

typedef __attribute__((ext_vector_type(8))) __bf16 bf16x8;
typedef __attribute__((ext_vector_type(4))) float f32x4;
typedef __attribute__((ext_vector_type(8))) unsigned short ushort8;

static __device__ inline unsigned short bfbits(__bf16 b) {
  union { __bf16 x; unsigned short u; } c; c.x = b; return c.u;
}
static __device__ inline void split2(float v, unsigned short& h, unsigned short& l) {
  __bf16 hb = (__bf16)v;
  float hf = (float)hb;
  __bf16 lb = (__bf16)(v - hf);
  h = bfbits(hb); l = bfbits(lb);
}

// Packed fragment layout for [R rows][K k] bf16 (R%16==0, K%32==0):
// 16x32 tile (rt,kt); chunk-in-tile = ((k>>3)&3)*16 + (r&15) == MFMA lane id.
static __device__ inline size_t pchunk(int r, int k, int NT) {
  return ((size_t)(r >> 4) * NT + (k >> 5)) * 64 + (((k >> 3) & 3) << 4) + (r & 15);
}

static __device__ inline void tsplit_body(const float* in, unsigned short* oh, unsigned short* ol,
                                          int R, int C, int c) {
  int lane = c & 63, tile = c >> 6;
  int NT = R >> 5;
  int kt = tile % NT, jt = tile / NT;
  int j = jt * 16 + (lane & 15);
  int k = kt * 32 + (lane >> 4) * 8;
  ushort8 hv, lv;
#pragma unroll
  for (int e = 0; e < 8; ++e) {
    unsigned short he, le;
    split2(in[(size_t)(k + e) * C + j], he, le);
    hv[e] = he; lv[e] = le;
  }
  *(ushort8*)&oh[(size_t)c * 8] = hv;
  *(ushort8*)&ol[(size_t)c * 8] = lv;
}

// ---------------- fused prep: edge histogram + weight conversions + p-norms ----------------

__global__ __launch_bounds__(256) void prep_all(
    const int* __restrict__ esrc, const int* __restrict__ edst,
    int* __restrict__ cnt_src, int* __restrict__ cnt_dst,
    const float* w0, const float* w1, const float* w2, const float* w3, const float* w4,
    unsigned short* o0h, unsigned short* o0l, unsigned short* o1h, unsigned short* o1l,
    unsigned short* o2h, unsigned short* o2l, unsigned short* o3h, unsigned short* o3l,
    unsigned short* o4h, unsigned short* o4l,
    const float* p0, const float* p1, float* pnrm) {
  __shared__ float red[4];
  int b = blockIdx.x;
  int tid = threadIdx.x;
  if (b < EE / 256) {
    int e = b * 256 + tid;
    atomicAdd(&cnt_src[esrc[e]], 1);
    atomicAdd(&cnt_dst[edst[e]], 1);
  } else if (b < EE / 256 + 288) {
    int g = (b - EE / 256) * 256 + tid;
    if (g < 4096)        tsplit_body(w0, o0h, o0l, 128, 256, g);
    else if (g < 20480)  tsplit_body(w1, o1h, o1l, 256, 512, g - 4096);
    else if (g < 53248)  tsplit_body(w2, o2h, o2l, 512, 512, g - 20480);
    else if (g < 69632)  tsplit_body(w3, o3h, o3l, 512, 256, g - 53248);
    else                 tsplit_body(w4, o4h, o4l, 256, 128, g - 69632);
  } else {
    int which = b - (EE / 256 + 288);
    const float* p = which ? p1 : p0;
    int C = which ? 512 : 256;
    float acc = 0.f;
    for (int j = tid; j < C; j += 256) { float v = p[j]; acc += v * v; }
    for (int o = 32; o > 0; o >>= 1) acc += __shfl_down(acc, o);
    if ((tid & 63) == 0) red[tid >> 6] = acc;
    __syncthreads();
    if (tid == 0) pnrm[which] = sqrtf(red[0] + red[1] + red[2] + red[3]);
  }
}

// both exclusive scans in one launch (register-serial + 1024-partial scan); block 0 emits dis0
__global__ __launch_bounds__(1024) void scan2(const int* __restrict__ cnt_dst,
                                              const int* __restrict__ cnt_src,
                                              int* __restrict__ csc_off, int* __restrict__ csr_off,
                                              float* __restrict__ dis0, int n) {
  __shared__ int part[1024];
  const int* in = blockIdx.x ? cnt_src : cnt_dst;
  int* out = blockIdx.x ? csr_off : csc_off;
  int tid = threadIdx.x;
  int base = tid * 4;
  int v[4];
  int s = 0;
#pragma unroll
  for (int e = 0; e < 4; ++e) {
    int x = in[base + e];
    v[e] = x; s += x;
    if (blockIdx.x == 0) dis0[base + e] = rsqrtf((float)x + 1.0f);
  }
  part[tid] = s;
  __syncthreads();
  for (int off2 = 1; off2 < 1024; off2 <<= 1) {
    int t = (tid >= off2) ? part[tid - off2] : 0;
    __syncthreads();
    part[tid] += t;
    __syncthreads();
  }
  int run = part[tid] - s;  // exclusive prefix of this thread's chunk
#pragma unroll
  for (int e = 0; e < 4; ++e) { run += v[e]; out[base + e + 1] = run; }
  if (tid == 0) out[0] = 0;
}

__global__ void scatter_kernel(const int* __restrict__ src, const int* __restrict__ dst,
                               const int* __restrict__ csc_off, const int* __restrict__ csr_off,
                               int* __restrict__ fill_dst, int* __restrict__ fill_src,
                               int* __restrict__ csc_src, int* __restrict__ csr_dst, int E) {
  int e = blockIdx.x * blockDim.x + threadIdx.x;
  if (e < E) {
    int s = src[e], d = dst[e];
    int p = atomicAdd(&fill_dst[d], 1);
    csc_src[csc_off[d] + p] = s;
    int q = atomicAdd(&fill_src[s], 1);
    csr_dst[csr_off[s] + q] = d;
  }
}

// ---------------- scoring / topk ----------------

__global__ void score_key(const float* __restrict__ X, const float* __restrict__ p,
                          const float* __restrict__ pn, float* __restrict__ s,
                          unsigned long long* __restrict__ keys, int C) {
  int i = blockIdx.x;
  int tid = threadIdx.x;
  float acc = 0.f;
  for (int j = tid; j < C; j += 256) acc += X[(size_t)i * C + j] * p[j];
  for (int o = 32; o > 0; o >>= 1) acc += __shfl_down(acc, o);
  __shared__ float red[4];
  if ((tid & 63) == 0) red[tid >> 6] = acc;
  __syncthreads();
  if (tid == 0) {
    float sv = tanhf((red[0] + red[1] + red[2] + red[3]) / pn[0]);
    s[i] = sv;
    unsigned u = __float_as_uint(sv);
    unsigned m = (u & 0x80000000u) ? ~u : (u | 0x80000000u);
    keys[i] = (((unsigned long long)(~m)) << 32) | (unsigned)i;  // desc value, asc index
  }
}

// partial rank: block (bx,by) counts keys[by*64..+64) against candidates [bx*256..+256)
__global__ __launch_bounds__(256) void rank_count(const unsigned long long* __restrict__ keys,
                                                  int* __restrict__ rank) {
  __shared__ unsigned long long kk[64];
  int tid = threadIdx.x;
  int cand = blockIdx.x * 256 + tid;
  int base = blockIdx.y * 64;
  if (tid < 64) kk[tid] = keys[base + tid];
  __syncthreads();
  unsigned long long kc = keys[cand];
  int c = 0;
#pragma unroll
  for (int t = 0; t < 64; ++t) c += (kk[t] < kc) ? 1 : 0;
  atomicAdd(&rank[cand], c);
}

// place by rank; optionally emit cntk (1 if kept) for the sparse-deg path
__global__ void rank_place(const float* __restrict__ s, const int* __restrict__ rank, int k, int n,
                           int* __restrict__ kept, int* __restrict__ perm, float* __restrict__ vals,
                           int* __restrict__ cntk) {
  int i = blockIdx.x * blockDim.x + threadIdx.x;
  if (i < n) {
    int r = rank[i];
    int isk = (r < k) ? 1 : 0;
    if (isk) { perm[r] = i; vals[r] = s[i]; kept[i] = r; }
    else kept[i] = -1;
    if (cntk) cntk[i] = isk;
  }
}

// pool-gather + gate + dis-scale + transpose-split packed ([256 ch][2048 nodes])
__global__ void pool_tsplit_p(const float* __restrict__ X, const int* __restrict__ perm,
                              const float* __restrict__ vals, const float* __restrict__ dis,
                              unsigned short* __restrict__ h, unsigned short* __restrict__ l) {
  int c = blockIdx.x * blockDim.x + threadIdx.x;
  int tile = c >> 6, lno = c & 63;
  int kt = tile & 63, jt = tile >> 6;   // NT = 2048/32 = 64
  int j = jt * 16 + (lno & 15);
  int k0 = kt * 32 + (lno >> 4) * 8;
  ushort8 hv, lv;
#pragma unroll
  for (int e = 0; e < 8; ++e) {
    int node = k0 + e;
    float sc = vals[node] * dis[node];
    float v = X[(size_t)perm[node] * 256 + j] * sc;
    unsigned short he, le;
    split2(v, he, le);
    hv[e] = he; lv[e] = le;
  }
  *(ushort8*)&h[(size_t)c * 8] = hv;
  *(ushort8*)&l[(size_t)c * 8] = lv;
}

// fused pool1 siblings: pooled-row packed split (blocks 0..255) + two packed gathers (256..2303)
__global__ __launch_bounds__(256) void pool1_misc(
    const float* __restrict__ res1, const int* __restrict__ perm1, const float* __restrict__ vals1,
    unsigned short* __restrict__ x2h, unsigned short* __restrict__ x2l,
    const unsigned short* __restrict__ B1rm, const unsigned short* __restrict__ B1t,
    unsigned short* __restrict__ Gh2, unsigned short* __restrict__ Hh2) {
  int b = blockIdx.x;
  int tid = threadIdx.x;
  if (b < 256) {
    int c = b * 256 + tid;                // over NP2*512/8 chunks
    int lane = c & 63, tile = c >> 6;
    int kt = tile & 15, rt = tile >> 4;   // NT = 512/32 = 16
    int r = rt * 16 + (lane & 15);
    int k0 = kt * 32 + (lane >> 4) * 8;
    float v = vals1[r];
    const float* src = res1 + (size_t)perm1[r] * 512 + k0;
    ushort8 hv, lv;
#pragma unroll
    for (int e = 0; e < 8; ++e) {
      unsigned short he, le;
      split2(src[e] * v, he, le);
      hv[e] = he; lv[e] = le;
    }
    *(ushort8*)&x2h[(size_t)c * 8] = hv;
    *(ushort8*)&x2l[(size_t)c * 8] = lv;
  } else {
    int idx = b - 256;
    int mat = idx >> 10;
    int c = (idx & 1023) * 256 + tid;     // over NP2*NP1/8 chunks
    const unsigned short* in = mat ? B1t : B1rm;
    unsigned short* outp = mat ? Hh2 : Gh2;
    const int NT = NP1 >> 5;              // 64
    int lane = c & 63, tile = c >> 6;
    int kt = tile % NT, at = tile / NT;
    int a = at * 16 + (lane & 15);
    int sub = lane >> 4;
    int p = perm1[a];
    size_t sc = ((size_t)(p >> 4) * NT + kt) * 64 + sub * 16 + (p & 15);
    *(ushort8*)&outp[(size_t)c * 8] = *(const ushort8*)&in[sc * 8];
  }
}

// ---------------- augment 0 (fused): sparse 2-path rows (8 waves) + kept-edge counts ----------------

__global__ __launch_bounds__(512) void augcnt(const int* __restrict__ csr_off,
                                              const int* __restrict__ csr_dst,
                                              const int* __restrict__ kept,
                                              const int* __restrict__ perm,
                                              unsigned short* __restrict__ rm,
                                              const int* __restrict__ esrc,
                                              const int* __restrict__ edst,
                                              int* __restrict__ cntk) {
  __shared__ float acc[NP1];
  int b = blockIdx.x;
  if (b < NP1) {
    int ki = b;
    int r = perm[ki];
    for (int t = threadIdx.x; t < NP1; t += 512) acc[t] = 0.f;
    __syncthreads();
    int s = csr_off[r], e = csr_off[r + 1];
    int nm = e - s;
    int wave = threadIdx.x >> 6, lane = threadIdx.x & 63;
    for (int m = wave; m <= nm; m += 8) {
      int k = (m < nm) ? csr_dst[s + m] : r;
      int s2 = csr_off[k], e2 = csr_off[k + 1];
      int n2 = e2 - s2;
      for (int t = lane; t <= n2; t += 64) {
        int j = (t < n2) ? csr_dst[s2 + t] : k;
        int kj = kept[j];
        if (kj >= 0) atomicAdd(&acc[kj], 1.0f);
      }
    }
    __syncthreads();
    if (threadIdx.x == 0) acc[ki] += 1.0f;  // +I on pooled graph
    __syncthreads();
    int tid = threadIdx.x;
    if (tid < 256) {
      ushort8 hv;
#pragma unroll
      for (int e8 = 0; e8 < 8; ++e8) hv[e8] = bfbits((__bf16)acc[tid * 8 + e8]);
      size_t dst = (((size_t)(ki >> 4)) * 64 + (tid >> 2)) * 64 + (size_t)(tid & 3) * 16 + (ki & 15);
      *(ushort8*)&rm[dst * 8] = hv;
    }
  } else {
    int e = (b - NP1) * 512 + threadIdx.x;
    if (kept[esrc[e]] >= 0) atomicAdd(&cntk[edst[e]], 1);
  }
}

// fused: packed transpose of B1rm (blocks 0..1023) + dis1 from sparse degs (blocks 1024..1535)
__global__ __launch_bounds__(256) void degtp(const unsigned short* __restrict__ in,
                                             unsigned short* __restrict__ outp, int n,
                                             const int* __restrict__ csc_off,
                                             const int* __restrict__ csc_src,
                                             const int* __restrict__ cntk,
                                             const int* __restrict__ perm,
                                             float* __restrict__ dis) {
  __shared__ unsigned short t[64][72];
  int b = blockIdx.x;
  if (b < 1024) {
    int r0 = (b >> 5) * 64, c0 = (b & 31) * 64;
    int NT = n >> 5;
    for (int q = threadIdx.x; q < 512; q += 256) {
      int lt = q >> 6, l = q & 63;
      int rt = lt >> 1, kt2 = lt & 1;
      int r = rt * 16 + (l & 15), k = kt2 * 32 + (l >> 4) * 8;
      ushort8 v = *(const ushort8*)&in[pchunk(r0 + r, c0 + k, NT) * 8];
      *(ushort8*)&t[r][k] = v;
    }
    __syncthreads();
    for (int q = threadIdx.x; q < 512; q += 256) {
      int lt = q >> 6, l = q & 63;
      int jt = lt >> 1, kt2 = lt & 1;
      int j = jt * 16 + (l & 15), k = kt2 * 32 + (l >> 4) * 8;
      ushort8 v;
#pragma unroll
      for (int e = 0; e < 8; ++e) v[e] = t[k + e][j];
      *(ushort8*)&outp[pchunk(c0 + j, r0 + k, NT) * 8] = v;
    }
  } else {
    int bid = b - 1024;
    int wid = threadIdx.x >> 6, lane = threadIdx.x & 63;
    int c = bid * 4 + wid;
    int r = perm[c];
    int s = csc_off[r], e = csc_off[r + 1];
    int sum = 0;
    for (int t2 = s + lane; t2 < e; t2 += 64) sum += cntk[csc_src[t2]];
    for (int o = 32; o > 0; o >>= 1) sum += __shfl_down(sum, o);
    if (lane == 0) dis[c] = rsqrtf((float)(sum + cntk[r] + 1));
  }
}

// ---------------- sparse aggregation ----------------

// A-first spmm fused with packed bf16 split output (gcn0)
template <int C>
__global__ __launch_bounds__(256) void spmm_presplit(const float* __restrict__ X,
                                                     const int* __restrict__ off,
                                                     const int* __restrict__ srcs,
                                                     const float* __restrict__ dis,
                                                     unsigned short* __restrict__ h,
                                                     unsigned short* __restrict__ l) {
  __shared__ float buf[4][C];
  constexpr int VEC = C / 64;
  int w = threadIdx.x >> 6, lane = threadIdx.x & 63;
  int c = blockIdx.x * 4 + w;
  int j = lane * VEC;
  float dc = dis[c];
  float acc[VEC];
  const float* p = X + (size_t)c * C + j;
#pragma unroll
  for (int u = 0; u < VEC; ++u) acc[u] = dc * p[u];
  int s = off[c], e = off[c + 1];
  for (int t = s; t < e; ++t) {
    int sr = srcs[t];
    float ds = dis[sr];
    const float* q = X + (size_t)sr * C + j;
#pragma unroll
    for (int u = 0; u < VEC; ++u) acc[u] += ds * q[u];
  }
#pragma unroll
  for (int u = 0; u < VEC; ++u) buf[w][j + u] = dc * acc[u];
  __syncthreads();
  constexpr int NC = C / 8;
  if (lane < NC) {
    const float* src = &buf[w][lane * 8];
    ushort8 hv, lv;
#pragma unroll
    for (int e2 = 0; e2 < 8; ++e2) {
      unsigned short he, le;
      split2(src[e2], he, le);
      hv[e2] = he; lv[e2] = le;
    }
    size_t ch = pchunk(c, lane * 8, C >> 5);
    *(ushort8*)&h[ch * 8] = hv;
    *(ushort8*)&l[ch * 8] = lv;
  }
}

// X-first spmm (gcn4): out = relu(dis[c]*(sum of pre-scaled rows) + bias)
template <int C>
__global__ __launch_bounds__(256) void spmm_gather_v(const float* __restrict__ Y,
                                                     const int* __restrict__ off,
                                                     const int* __restrict__ srcs,
                                                     const float* __restrict__ dis,
                                                     const float* __restrict__ bias,
                                                     float* __restrict__ out) {
  constexpr int VEC = C / 64;
  int w = threadIdx.x >> 6, lane = threadIdx.x & 63;
  int c = blockIdx.x * 4 + w;
  int j = lane * VEC;
  float acc[VEC];
  const float* p = Y + (size_t)c * C + j;
#pragma unroll
  for (int u = 0; u < VEC; ++u) acc[u] = p[u];
  int s = off[c], e = off[c + 1];
  for (int t = s; t < e; ++t) {
    const float* q = Y + (size_t)srcs[t] * C + j;
#pragma unroll
    for (int u = 0; u < VEC; ++u) acc[u] += q[u];
  }
  float d = dis[c];
  float* o = out + (size_t)c * C + j;
#pragma unroll
  for (int u = 0; u < VEC; ++u) o[u] = fmaxf(d * acc[u] + bias[j + u], 0.0f);
}

// ---------------- combines ----------------

// combine S partials -> packed bf16 hi/lo row-major (for Z = B1^T Xs)
template <int S>
__global__ void ep_zsplit(const float* __restrict__ p, unsigned short* __restrict__ h,
                          unsigned short* __restrict__ l, int M, int N) {
  int t = blockIdx.x * blockDim.x + threadIdx.x;
  int tile = t >> 6, w = t & 63;
  int NT = N >> 5;
  int rt = tile / NT, kt = tile % NT;
  int r = rt * 16 + (w & 15);
  int k = kt * 32 + (w >> 4) * 8;
  const float* p0 = p + (size_t)r * N + k;
  ushort8 hv, lv;
#pragma unroll
  for (int e = 0; e < 8; ++e) {
    float v = p0[e];
#pragma unroll
    for (int s = 1; s < S; ++s) v += p0[(size_t)s * M * N + e];
    unsigned short he, le;
    split2(v, he, le);
    hv[e] = he; lv[e] = le;
  }
  *(ushort8*)&h[(size_t)t * 8] = hv;
  *(ushort8*)&l[(size_t)t * 8] = lv;
}

// unpool + fold split-K epilogue: x = res[r] + (kept? relu(rs*(sum partials)+bias) : 0) -> packed split
template <int S, int RSQ>
__global__ void unpool_ep_split(const float* __restrict__ res, const float* __restrict__ pscr,
                                const int* __restrict__ kept, const float* __restrict__ rs,
                                const float* __restrict__ bias,
                                unsigned short* __restrict__ h, unsigned short* __restrict__ l,
                                int M, int C) {
  int c = blockIdx.x * blockDim.x + threadIdx.x;
  int lane = c & 63, tile = c >> 6;
  int NT = C >> 5;
  int kt = tile % NT, rt = tile / NT;
  int r = rt * 16 + (lane & 15);
  int j0 = kt * 32 + (lane >> 4) * 8;
  int kv = kept[r];
  float rsv = 0.f;
  if (kv >= 0) { rsv = rs[kv]; if (RSQ) rsv = rsqrtf(rsv); }
  ushort8 hv, lv;
#pragma unroll
  for (int e = 0; e < 8; ++e) {
    float v = res[(size_t)r * C + j0 + e];
    if (kv >= 0) {
      float a = 0.f;
#pragma unroll
      for (int s = 0; s < S; ++s) a += pscr[((size_t)s * M + kv) * C + j0 + e];
      v += fmaxf(rsv * a + bias[j0 + e], 0.0f);
    }
    unsigned short he, le;
    split2(v, he, le);
    hv[e] = he; lv[e] = le;
  }
  *(ushort8*)&h[(size_t)c * 8] = hv;
  *(ushort8*)&l[(size_t)c * 8] = lv;
}

// combine S partials (+I) -> PACKED transpose-split B2t directly, + column sums into deg
template <int S>
__global__ void ep_aug_cs2(const float* __restrict__ p, unsigned short* __restrict__ th,
                           unsigned short* __restrict__ tl, float* __restrict__ deg, int n) {
  int c = blockIdx.x * 256 + threadIdx.x;
  int r0 = blockIdx.y * 64;
  int NT = n >> 5;
  float cs = 0.f;
  for (int g = 0; g < 8; ++g) {
    float vbuf[8];
#pragma unroll
    for (int e = 0; e < 8; ++e) {
      int r = r0 + g * 8 + e;
      float v = 0.f;
#pragma unroll
      for (int s = 0; s < S; ++s) v += p[((size_t)s * n + r) * n + c];
      if (r == c) v += 1.0f;
      vbuf[e] = v;
      cs += v;
    }
    ushort8 hv, lv;
#pragma unroll
    for (int e = 0; e < 8; ++e) {
      unsigned short he, le;
      split2(vbuf[e], he, le);
      hv[e] = he; lv[e] = le;
    }
    size_t ch = pchunk(c, r0 + g * 8, NT);
    *(ushort8*)&th[ch * 8] = hv;
    *(ushort8*)&tl[ch * 8] = lv;
  }
  atomicAdd(&deg[c], cs);
}

// ---------------- shared GEMM epilogue ----------------
template <int EPI, int S, int RSQ>
static __device__ inline void gemm_epi(f32x4 a, int z, int ib, int j, int M, int N,
                                       const float* rs, const float* bias,
                                       float* C, unsigned short* Th, unsigned short* Tl) {
  if constexpr (S > 1) {
#pragma unroll
    for (int r = 0; r < 4; ++r) C[((size_t)z * M + ib + r) * N + j] = a[r];
  } else if constexpr (EPI == 0) {
#pragma unroll
    for (int r = 0; r < 4; ++r) C[(size_t)(ib + r) * N + j] = a[r];
  } else if constexpr (EPI == 1) {
#pragma unroll
    for (int r = 0; r < 4; ++r) {
      float rsv = rs[ib + r];
      if (RSQ) rsv = rsqrtf(rsv);
      C[(size_t)(ib + r) * N + j] = rsv * a[r];
    }
  } else if constexpr (EPI == 2) {
    unsigned long long hp = 0, lp = 0;
#pragma unroll
    for (int r = 0; r < 4; ++r) {
      float rsv = rs[ib + r];
      if (RSQ) rsv = rsqrtf(rsv);
      unsigned short hv, lv;
      split2(rsv * a[r], hv, lv);
      hp |= ((unsigned long long)hv) << (16 * r);
      lp |= ((unsigned long long)lv) << (16 * r);
    }
    size_t c = pchunk(j, ib, M >> 5);
    *(unsigned long long*)&Th[c * 8 + (ib & 7)] = hp;
    *(unsigned long long*)&Tl[c * 8 + (ib & 7)] = lp;
  } else if constexpr (EPI == 3) {
#pragma unroll
    for (int r = 0; r < 4; ++r) {
      float rsv = rs[ib + r];
      if (RSQ) rsv = rsqrtf(rsv);
      C[(size_t)(ib + r) * N + j] = fmaxf(rsv * a[r] + bias[j], 0.0f);
    }
  } else {
#pragma unroll
    for (int r = 0; r < 4; ++r)
      C[(size_t)(ib + r) * N + j] = fmaxf(a[r] + bias[j], 0.0f);
  }
}

// ---------------- bf16-split MFMA GEMM, 32x32/wave, 4 waves (64x64 tile) ----------------
template <int EPI, int AL, int BL, int KK, int S, int RSQ>
__global__ __launch_bounds__(256) void gemm16(
    const unsigned short* __restrict__ Ah, const unsigned short* __restrict__ Al,
    const unsigned short* __restrict__ Bh, const unsigned short* __restrict__ Bl,
    int M, int N, const float* __restrict__ rs, const float* __restrict__ bias,
    float* __restrict__ C, unsigned short* __restrict__ Th, unsigned short* __restrict__ Tl) {
  static_assert(KK % 32 == 0, "K");
  constexpr int KSTEPS = KK / 32;
  const int NT = (KK * S) >> 5;
  const int gx = gridDim.x;
  int id = blockIdx.y * gx + blockIdx.x;
  int cpx = (gx * gridDim.y) >> 3;
  int sid = (id & 7) * cpx + (id >> 3);
  const int bx = sid % gx, by = sid / gx;
  const int z = (S > 1) ? blockIdx.z : 0;
  const int wid = threadIdx.x >> 6, lane = threadIdx.x & 63;
  const int i0 = by * 64 + (wid >> 1) * 32;
  const int j0 = bx * 64 + (wid & 1) * 32;
  const int lr = lane & 15, lk = lane >> 4;
  size_t aoff[2], boff[2];
#pragma unroll
  for (int t = 0; t < 2; ++t) {
    aoff[t] = ((size_t)((i0 >> 4) + t) * NT + z * (KK >> 5)) * 512 + lane * 8;
    boff[t] = ((size_t)((j0 >> 4) + t) * NT + z * (KK >> 5)) * 512 + lane * 8;
  }
  const f32x4 zf = {0.f, 0.f, 0.f, 0.f};
  f32x4 acc[2][2];
  acc[0][0] = zf; acc[0][1] = zf; acc[1][0] = zf; acc[1][1] = zf;

  bf16x8 ahf[4][2], bhf[4][2], alf[4][2], blf[4][2];
  auto loadk = [&](int kk, int b) {
    size_t o = (size_t)kk * 512;
    ahf[b][0] = *(const bf16x8*)(Ah + aoff[0] + o);
    ahf[b][1] = *(const bf16x8*)(Ah + aoff[1] + o);
    bhf[b][0] = *(const bf16x8*)(Bh + boff[0] + o);
    bhf[b][1] = *(const bf16x8*)(Bh + boff[1] + o);
    if constexpr (AL) {
      alf[b][0] = *(const bf16x8*)(Al + aoff[0] + o);
      alf[b][1] = *(const bf16x8*)(Al + aoff[1] + o);
    }
    if constexpr (BL) {
      blf[b][0] = *(const bf16x8*)(Bl + boff[0] + o);
      blf[b][1] = *(const bf16x8*)(Bl + boff[1] + o);
    }
  };
  auto domm = [&](int b) {
#pragma unroll
    for (int am = 0; am < 2; ++am)
#pragma unroll
      for (int bn = 0; bn < 2; ++bn) {
        acc[am][bn] = __builtin_amdgcn_mfma_f32_16x16x32_bf16(ahf[b][am], bhf[b][bn], acc[am][bn], 0, 0, 0);
        if constexpr (BL)
          acc[am][bn] = __builtin_amdgcn_mfma_f32_16x16x32_bf16(ahf[b][am], blf[b][bn], acc[am][bn], 0, 0, 0);
        if constexpr (AL)
          acc[am][bn] = __builtin_amdgcn_mfma_f32_16x16x32_bf16(alf[b][am], bhf[b][bn], acc[am][bn], 0, 0, 0);
      }
  };

  loadk(0, 0);
  if constexpr (KSTEPS > 1) loadk(1, 1);
  if constexpr (KSTEPS > 2) loadk(2, 2);
#pragma unroll
  for (int kk = 0; kk < KSTEPS; ++kk) {
    const int cur = kk & 3;
    if (kk + 3 < KSTEPS) loadk(kk + 3, (cur + 3) & 3);
    domm(cur);
  }

#pragma unroll
  for (int am = 0; am < 2; ++am)
#pragma unroll
    for (int bn = 0; bn < 2; ++bn)
      gemm_epi<EPI, S, RSQ>(acc[am][bn], z, i0 + 16 * am + lk * 4, j0 + 16 * bn + lr,
                            M, N, rs, bias, C, Th, Tl);
}

// ---------------- bf16-split MFMA GEMM, 32x32/wave, 2 waves (64x32 tile) ----------------
template <int EPI, int AL, int BL, int KK, int S, int RSQ>
__global__ __launch_bounds__(128) void gemm8(
    const unsigned short* __restrict__ Ah, const unsigned short* __restrict__ Al,
    const unsigned short* __restrict__ Bh, const unsigned short* __restrict__ Bl,
    int M, int N, const float* __restrict__ rs, const float* __restrict__ bias,
    float* __restrict__ C, unsigned short* __restrict__ Th, unsigned short* __restrict__ Tl) {
  static_assert(KK % 32 == 0, "K");
  constexpr int KSTEPS = KK / 32;
  const int NT = (KK * S) >> 5;
  const int gx = gridDim.x;
  int id = blockIdx.y * gx + blockIdx.x;
  int cpx = (gx * gridDim.y) >> 3;
  int sid = (id & 7) * cpx + (id >> 3);
  const int bx = sid % gx, by = sid / gx;
  const int z = (S > 1) ? blockIdx.z : 0;
  const int wid = threadIdx.x >> 6, lane = threadIdx.x & 63;
  const int i0 = by * 64 + wid * 32;   // 2 waves stacked on M
  const int j0 = bx * 32;
  const int lr = lane & 15, lk = lane >> 4;
  size_t aoff[2], boff[2];
#pragma unroll
  for (int t = 0; t < 2; ++t) {
    aoff[t] = ((size_t)((i0 >> 4) + t) * NT + z * (KK >> 5)) * 512 + lane * 8;
    boff[t] = ((size_t)((j0 >> 4) + t) * NT + z * (KK >> 5)) * 512 + lane * 8;
  }
  const f32x4 zf = {0.f, 0.f, 0.f, 0.f};
  f32x4 acc[2][2];
  acc[0][0] = zf; acc[0][1] = zf; acc[1][0] = zf; acc[1][1] = zf;

  bf16x8 ahf[4][2], bhf[4][2], alf[4][2], blf[4][2];
  auto loadk = [&](int kk, int b) {
    size_t o = (size_t)kk * 512;
    ahf[b][0] = *(const bf16x8*)(Ah + aoff[0] + o);
    ahf[b][1] = *(const bf16x8*)(Ah + aoff[1] + o);
    bhf[b][0] = *(const bf16x8*)(Bh + boff[0] + o);
    bhf[b][1] = *(const bf16x8*)(Bh + boff[1] + o);
    if constexpr (AL) {
      alf[b][0] = *(const bf16x8*)(Al + aoff[0] + o);
      alf[b][1] = *(const bf16x8*)(Al + aoff[1] + o);
    }
    if constexpr (BL) {
      blf[b][0] = *(const bf16x8*)(Bl + boff[0] + o);
      blf[b][1] = *(const bf16x8*)(Bl + boff[1] + o);
    }
  };
  auto domm = [&](int b) {
#pragma unroll
    for (int am = 0; am < 2; ++am)
#pragma unroll
      for (int bn = 0; bn < 2; ++bn) {
        acc[am][bn] = __builtin_amdgcn_mfma_f32_16x16x32_bf16(ahf[b][am], bhf[b][bn], acc[am][bn], 0, 0, 0);
        if constexpr (BL)
          acc[am][bn] = __builtin_amdgcn_mfma_f32_16x16x32_bf16(ahf[b][am], blf[b][bn], acc[am][bn], 0, 0, 0);
        if constexpr (AL)
          acc[am][bn] = __builtin_amdgcn_mfma_f32_16x16x32_bf16(alf[b][am], bhf[b][bn], acc[am][bn], 0, 0, 0);
      }
  };

  loadk(0, 0);
  if constexpr (KSTEPS > 1) loadk(1, 1);
  if constexpr (KSTEPS > 2) loadk(2, 2);
#pragma unroll
  for (int kk = 0; kk < KSTEPS; ++kk) {
    const int cur = kk & 3;
    if (kk + 3 < KSTEPS) loadk(kk + 3, (cur + 3) & 3);
    domm(cur);
  }

#pragma unroll
  for (int am = 0; am < 2; ++am)
#pragma unroll
    for (int bn = 0; bn < 2; ++bn)
      gemm_epi<EPI, S, RSQ>(acc[am][bn], z, i0 + 16 * am + lk * 4, j0 + 16 * bn + lr,
                            M, N, rs, bias, C, Th, Tl);
}

// ---------------- bf16-split MFMA GEMM, 64x64/wave (split-K partials) ----------------
template <int AL, int BL, int KK, int S>
__global__ __launch_bounds__(256) void gemm64(
    const unsigned short* __restrict__ Ah, const unsigned short* __restrict__ Al,
    const unsigned short* __restrict__ Bh, const unsigned short* __restrict__ Bl,
    int M, int N, float* __restrict__ C) {
  static_assert(KK % 32 == 0, "K");
  constexpr int KSTEPS = KK / 32;
  const int NT = (KK * S) >> 5;
  const int gx = gridDim.x;
  int id = blockIdx.y * gx + blockIdx.x;
  int cpx = (gx * gridDim.y) >> 3;
  int sid = (id & 7) * cpx + (id >> 3);
  const int bx = sid % gx, by = sid / gx;
  const int z = blockIdx.z;
  const int wid = threadIdx.x >> 6, lane = threadIdx.x & 63;
  const int i0 = by * 128 + (wid >> 1) * 64;
  const int j0 = bx * 128 + (wid & 1) * 64;
  const int lr = lane & 15, lk = lane >> 4;
  size_t aoff[4], boff[4];
#pragma unroll
  for (int t = 0; t < 4; ++t) {
    aoff[t] = ((size_t)((i0 >> 4) + t) * NT + z * (KK >> 5)) * 512 + lane * 8;
    boff[t] = ((size_t)((j0 >> 4) + t) * NT + z * (KK >> 5)) * 512 + lane * 8;
  }
  const f32x4 zf = {0.f, 0.f, 0.f, 0.f};
  f32x4 acc[4][4];
#pragma unroll
  for (int a = 0; a < 4; ++a)
#pragma unroll
    for (int b = 0; b < 4; ++b) acc[a][b] = zf;

  bf16x8 ahf[2][4], bhf[2][4], alf[2][4], blf[2][4];
  auto loadk = [&](int kk, int b) {
    size_t o = (size_t)kk * 512;
#pragma unroll
    for (int t = 0; t < 4; ++t) {
      ahf[b][t] = *(const bf16x8*)(Ah + aoff[t] + o);
      bhf[b][t] = *(const bf16x8*)(Bh + boff[t] + o);
      if constexpr (AL) alf[b][t] = *(const bf16x8*)(Al + aoff[t] + o);
      if constexpr (BL) blf[b][t] = *(const bf16x8*)(Bl + boff[t] + o);
    }
  };
  auto domm = [&](int b) {
#pragma unroll
    for (int am = 0; am < 4; ++am)
#pragma unroll
      for (int bn = 0; bn < 4; ++bn) {
        acc[am][bn] = __builtin_amdgcn_mfma_f32_16x16x32_bf16(ahf[b][am], bhf[b][bn], acc[am][bn], 0, 0, 0);
        if constexpr (BL)
          acc[am][bn] = __builtin_amdgcn_mfma_f32_16x16x32_bf16(ahf[b][am], blf[b][bn], acc[am][bn], 0, 0, 0);
        if constexpr (AL)
          acc[am][bn] = __builtin_amdgcn_mfma_f32_16x16x32_bf16(alf[b][am], bhf[b][bn], acc[am][bn], 0, 0, 0);
      }
  };

  loadk(0, 0);
#pragma unroll
  for (int kk = 0; kk < KSTEPS; ++kk) {
    const int cur = kk & 1;
    if (kk + 1 < KSTEPS) loadk(kk + 1, cur ^ 1);
    domm(cur);
  }

#pragma unroll
  for (int am = 0; am < 4; ++am)
#pragma unroll
    for (int bn = 0; bn < 4; ++bn) {
      int ib = i0 + 16 * am + lk * 4;
      int j = j0 + 16 * bn + lr;
      f32x4 a = acc[am][bn];
#pragma unroll
      for (int r = 0; r < 4; ++r) C[((size_t)z * M + ib + r) * N + j] = a[r];
    }
}

// ---------------- launch ----------------

extern "C" void kernel_launch(void* const* d_in, const int* in_sizes, int n_in,
                              void* d_out, int out_size, void* d_ws, size_t ws_size,
                              hipStream_t stream) {
  (void)in_sizes; (void)n_in; (void)out_size; (void)ws_size;
  const float* x  = (const float*)d_in[0];
  const int* ei   = (const int*)d_in[1];
  const int* esrc = ei;
  const int* edst = ei + EE;
  const float* w0 = (const float*)d_in[2];
  const float* b0 = (const float*)d_in[3];
  const float* w1 = (const float*)d_in[4];
  const float* b1 = (const float*)d_in[5];
  const float* w2 = (const float*)d_in[6];
  const float* b2 = (const float*)d_in[7];
  const float* w3 = (const float*)d_in[8];
  const float* b3 = (const float*)d_in[9];
  const float* w4 = (const float*)d_in[10];
  const float* b4 = (const float*)d_in[11];
  const float* p0 = (const float*)d_in[12];
  const float* p1 = (const float*)d_in[13];
  float* out = (float*)d_out;

  char* ws = (char*)d_ws;
  size_t off = 0;
  auto alloc = [&](size_t b) { void* p = ws + off; off += (b + 255) & ~(size_t)255; return p; };

  int* csc_off = (int*)alloc(4 * (NN + 1));
  int* csr_off = (int*)alloc(4 * (NN + 1));
  int* csc_src = (int*)alloc(4 * EE);
  int* csr_dst = (int*)alloc(4 * EE);

  // zeroed region: 4 count arrays + deg2 + rank0 + rank1
  size_t zero_bytes = 4 * NN * 4 + 4 * NP2 + 4 * NN + 4 * NP1;
  int* cnts    = (int*)alloc(zero_bytes);
  int* cnt_dst = cnts;
  int* cnt_src = cnts + NN;
  int* fill_dst = cnts + 2 * NN;
  int* fill_src = cnts + 3 * NN;
  float* deg2 = (float*)(cnts + 4 * NN);
  int* rank0 = (int*)(deg2 + NP2);
  int* rank1 = rank0 + NN;

  int* cntk  = (int*)alloc(4 * NN);
  int* kept0 = (int*)alloc(4 * NN);
  int* perm0 = (int*)alloc(4 * NP1);
  int* kept1 = (int*)alloc(4 * NP1);
  int* perm1 = (int*)alloc(4 * NP2);
  float* dis0 = (float*)alloc(4 * NN);
  float* dis1 = (float*)alloc(4 * NP1);
  float* pnrm = (float*)alloc(8);
  float* s0   = (float*)alloc(4 * NN);
  float* vals0 = (float*)alloc(4 * NP1);
  float* s1   = (float*)alloc(4 * NP1);
  float* vals1 = (float*)alloc(4 * NP2);
  unsigned long long* keys0 = (unsigned long long*)alloc(8 * NN);
  unsigned long long* keys1 = (unsigned long long*)alloc(8 * NP1);

  const size_t MB = 1024 * 1024;
  // 16MB region: Gh2/Hh2 gathers (0..8MB); later B2t splits (4..8MB, over dead Hh2)
  char* regB1 = (char*)alloc(16 * MB);
  unsigned short* Gh2 = (unsigned short*)regB1;
  unsigned short* Hh2 = (unsigned short*)(regB1 + 4 * MB);
  unsigned short* B2th = (unsigned short*)(regB1 + 4 * MB);
  unsigned short* B2tl = (unsigned short*)(regB1 + 6 * MB);
  float* pscr = (float*)alloc(16 * MB);  // split-K partials

  unsigned short* B1rm = (unsigned short*)alloc(8 * MB);  // packed bf16 (exact)
  unsigned short* B1t  = (unsigned short*)alloc(8 * MB);  // packed bf16 transpose (exact)
  float* res0 = (float*)alloc(4 * MB);
  float* res1 = (float*)alloc(4 * MB);
  float* yreg = (float*)alloc(4 * MB);   // y4 (4096x128)
  char* ytreg = (char*)alloc(4 * MB);    // Y2t h+l / Y3t h+l
  unsigned short* Y2th = (unsigned short*)ytreg;
  unsigned short* Y2tl = (unsigned short*)(ytreg + 1 * MB);
  unsigned short* Y3th = (unsigned short*)ytreg;
  unsigned short* Y3tl = (unsigned short*)(ytreg + 1 * MB);
  char* xsreg = (char*)alloc(4 * MB);    // x3 h+l -> x4 h+l
  unsigned short* x3h = (unsigned short*)xsreg;
  unsigned short* x3l = (unsigned short*)(xsreg + 2 * MB);
  unsigned short* x4h = (unsigned short*)xsreg;
  unsigned short* x4l = (unsigned short*)(xsreg + 2 * MB);
  unsigned short* xh = (unsigned short*)alloc(1 * MB);   // Gh (4096x128 split)
  unsigned short* xl = (unsigned short*)alloc(1 * MB);
  char* xsm = (char*)alloc(2 * MB);      // x1t h+l -> Z h+l -> x2 h+l
  unsigned short* x1th = (unsigned short*)xsm;
  unsigned short* x1tl = (unsigned short*)(xsm + 1 * MB);
  unsigned short* Zh = (unsigned short*)xsm;
  unsigned short* Zl = (unsigned short*)(xsm + 1 * MB);
  unsigned short* x2h = (unsigned short*)xsm;
  unsigned short* x2l = (unsigned short*)(xsm + 1 * MB);
  unsigned short* Wt0h = (unsigned short*)alloc(256 * 128 * 2);
  unsigned short* Wt0l = (unsigned short*)alloc(256 * 128 * 2);
  unsigned short* Wt1h = (unsigned short*)alloc(512 * 256 * 2);
  unsigned short* Wt1l = (unsigned short*)alloc(512 * 256 * 2);
  unsigned short* Wt2h = (unsigned short*)alloc(512 * 512 * 2);
  unsigned short* Wt2l = (unsigned short*)alloc(512 * 512 * 2);
  unsigned short* Wt3h = (unsigned short*)alloc(256 * 512 * 2);
  unsigned short* Wt3l = (unsigned short*)alloc(256 * 512 * 2);
  unsigned short* Wt4h = (unsigned short*)alloc(128 * 256 * 2);
  unsigned short* Wt4l = (unsigned short*)alloc(128 * 256 * 2);

  hipMemsetAsync(cnts, 0, zero_bytes, stream);

  // graph build + weight conversions + p-norms
  prep_all<<<EE / 256 + 288 + 2, 256, 0, stream>>>(
      esrc, edst, cnt_src, cnt_dst, w0, w1, w2, w3, w4,
      Wt0h, Wt0l, Wt1h, Wt1l, Wt2h, Wt2l, Wt3h, Wt3l, Wt4h, Wt4l, p0, p1, pnrm);
  scan2<<<2, 1024, 0, stream>>>(cnt_dst, cnt_src, csc_off, csr_off, dis0, NN);
  scatter_kernel<<<EE / 256, 256, 0, stream>>>(esrc, edst, csc_off, csr_off,
                                               fill_dst, fill_src, csc_src, csr_dst, EE);

  // gcn0 (A-first): G = dis ⊙ (M+I)^T (dis ⊙ x) -> packed split; res0 = relu(G W0 + b0)
  spmm_presplit<128><<<NN / 4, 256, 0, stream>>>(x, csc_off, csc_src, dis0, xh, xl);
  gemm16<4, 1, 1, 128, 1, 0><<<dim3(4, 64), 256, 0, stream>>>(xh, xl, Wt0h, Wt0l,
                                                              NN, 256, nullptr, b0, res0, nullptr, nullptr);

  // pool0
  score_key<<<NN, 256, 0, stream>>>(res0, p0, pnrm + 0, s0, keys0, 256);
  rank_count<<<dim3(NN / 256, NN / 64), 256, 0, stream>>>(keys0, rank0);
  rank_place<<<NN / 256, 256, 0, stream>>>(s0, rank0, NP1, NN, kept0, perm0, vals0, cntk);

  // augment0 (fused, 8 waves/row): packed B1rm rows + kept-edge counts; then transpose + dis1
  augcnt<<<NP1 + EE / 512, 512, 0, stream>>>(csr_off, csr_dst, kept0, perm0, B1rm,
                                             esrc, edst, cntk);
  degtp<<<1024 + NP1 / 4, 256, 0, stream>>>(B1rm, B1t, NP1, csc_off, csc_src, cntk, perm0, dis1);

  // gcn1 (A-first): Z = B1^T (dis1 ⊙ x1); res1 = relu(dis1 ⊙ (Z W1) + b1)
  pool_tsplit_p<<<(NP1 * 256 / 8) / 256, 256, 0, stream>>>(res0, perm0, vals0, dis1, x1th, x1tl);
  gemm64<0, 1, 256, 8><<<dim3(2, 16, 8), 256, 0, stream>>>(B1t, nullptr, x1th, x1tl,
                                                           NP1, 256, pscr);
  ep_zsplit<8><<<(NP1 * 256 / 8) / 256, 256, 0, stream>>>(pscr, Zh, Zl, NP1, 256);
  gemm16<3, 1, 1, 256, 1, 0><<<dim3(8, 32), 256, 0, stream>>>(Zh, Zl, Wt1h, Wt1l,
                                                              NP1, 512, dis1, b1, res1, nullptr, nullptr);

  // pool1
  score_key<<<NP1, 256, 0, stream>>>(res1, p1, pnrm + 1, s1, keys1, 512);
  rank_count<<<dim3(NP1 / 256, NP1 / 64), 256, 0, stream>>>(keys1, rank1);
  rank_place<<<NP1 / 256, 256, 0, stream>>>(s1, rank1, NP2, NP1, kept1, perm1, vals1, nullptr);

  // pool1 pooled-features split + both packed gathers (1 fused launch)
  pool1_misc<<<256 + 2048, 256, 0, stream>>>(res1, perm1, vals1, x2h, x2l,
                                             B1rm, B1t, Gh2, Hh2);

  // augment1: dense exact GEMM (split-K) -> packed B2t + colsums
  gemm64<0, 0, 512, 4><<<dim3(8, 8, 4), 256, 0, stream>>>(Gh2, nullptr, Hh2, nullptr,
                                                          NP2, NP2, pscr);
  ep_aug_cs2<4><<<dim3(NP2 / 256, NP2 / 64), 256, 0, stream>>>(pscr, B2th, B2tl, deg2, NP2);

  // gcn2 (bottleneck, X-first); dis2 = rsqrt(deg2) folded into epilogues
  gemm8<2, 1, 1, 512, 1, 1><<<dim3(16, 16), 128, 0, stream>>>(x2h, x2l, Wt2h, Wt2l,
                                                              NP2, 512, deg2, nullptr, nullptr, Y2th, Y2tl);
  gemm16<0, 1, 1, 512, 2, 0><<<dim3(8, 16, 2), 256, 0, stream>>>(B2th, B2tl, Y2th, Y2tl,
                                                                 NP2, 512, nullptr, nullptr, pscr, nullptr, nullptr);

  // up1: unpool + gcn2-combine folded, emit packed x3
  unpool_ep_split<2, 1><<<(NP1 * 512 / 8) / 256, 256, 0, stream>>>(res1, pscr, kept1, deg2, b2,
                                                                   x3h, x3l, NP2, 512);
  gemm8<2, 1, 1, 512, 1, 0><<<dim3(8, 32), 128, 0, stream>>>(x3h, x3l, Wt3h, Wt3l,
                                                             NP1, 256, dis1, nullptr, nullptr, Y3th, Y3tl);
  gemm64<0, 1, 256, 8><<<dim3(2, 16, 8), 256, 0, stream>>>(B1t, nullptr, Y3th, Y3tl,
                                                           NP1, 256, pscr);

  // up0: unpool + gcn3-combine folded, emit packed x4
  unpool_ep_split<8, 0><<<(NN * 256 / 8) / 256, 256, 0, stream>>>(res0, pscr, kept0, dis1, b3,
                                                                  x4h, x4l, NP1, 256);
  gemm8<1, 1, 1, 256, 1, 0><<<dim3(4, 64), 128, 0, stream>>>(x4h, x4l, Wt4h, Wt4l,
                                                             NN, 128, dis0, nullptr, yreg, nullptr, nullptr);
  spmm_gather_v<128><<<NN / 4, 256, 0, stream>>>(yreg, csc_off, csc_src, dis0, b4, out);
}